// Round 9
// baseline (1863.933 us; speedup 1.0000x reference)
//
#include <hip/hip_runtime.h>
#include <math.h>

#define BSZ 4
#define DM 256
#define LL 256
#define DI 512
#define NBL (BSZ * LL)  // 1024
#define REP 9           // diagnostic in-kernel repeat for chain kernels

// ---------------- dispatch 1: mean over W (blocks 0..1023) + Wf prep (1024..1535) ----------------
__global__ __launch_bounds__(256) void k_meanw_prep(const float* __restrict__ x0,
                                                    const float* __restrict__ in_w1,
                                                    const float* __restrict__ out_w0,
                                                    float* __restrict__ S0,
                                                    float* __restrict__ Wf) {
    __shared__ float smem[1664];
    int bl = blockIdx.x;
    int tid = threadIdx.x;
    if (bl < 1024) {
        int wv = tid >> 6, lane = tid & 63;
        const float4* x4 = (const float4*)x0;
        int rbase = bl * 256 + wv * 64;
        for (int i0 = 0; i0 < 64; i0 += 4) {
            float s[4];
#pragma unroll
            for (int j = 0; j < 4; ++j) {
                float4 v = x4[(size_t)(rbase + i0 + j) * 64 + lane];
                s[j] = (v.x + v.y) + (v.z + v.w);
            }
#pragma unroll
            for (int j = 0; j < 4; ++j) {
#pragma unroll
                for (int m = 32; m >= 1; m >>= 1) s[j] += __shfl_xor(s[j], m);
            }
            if (lane == 0) {
#pragma unroll
                for (int j = 0; j < 4; ++j) {
                    int rr = rbase + i0 + j;
                    int b = rr >> 16, d = (rr >> 8) & 255, h = rr & 255;
                    S0[((size_t)(b * LL) + h) * DM + d] = s[j] * (1.0f / 256.0f);
                }
            }
        }
    } else {
        float* As = smem;
        float* Bs = smem + 576;
        int t = bl - 1024;
        int e0 = (t >> 4) * 32, k0c = (t & 15) * 32;
        int tx = tid & 15, ty = tid >> 4;
        float acc00 = 0.f, acc01 = 0.f, acc10 = 0.f, acc11 = 0.f;
        for (int dm0 = 0; dm0 < 256; dm0 += 16) {
            float4 v;
            if (tid < 128) {
                int r = tid >> 2, q = tid & 3;
                v = *(const float4*)(in_w1 + (size_t)(e0 + r) * 256 + dm0 + 4 * q);
            } else {
                int idx = tid - 128;
                int r = idx >> 3, q = idx & 7;
                v = *(const float4*)(out_w0 + (size_t)(dm0 + r) * 512 + k0c + 4 * q);
            }
            __syncthreads();
            if (tid < 128) {
                int r = tid >> 2, q = tid & 3;
                As[(4 * q + 0) * 36 + r] = v.x;
                As[(4 * q + 1) * 36 + r] = v.y;
                As[(4 * q + 2) * 36 + r] = v.z;
                As[(4 * q + 3) * 36 + r] = v.w;
            } else {
                int idx = tid - 128;
                int r = idx >> 3, q = idx & 7;
                Bs[r * 36 + 4 * q + 0] = v.x;
                Bs[r * 36 + 4 * q + 1] = v.y;
                Bs[r * 36 + 4 * q + 2] = v.z;
                Bs[r * 36 + 4 * q + 3] = v.w;
            }
            __syncthreads();
#pragma unroll
            for (int kk = 0; kk < 16; ++kk) {
                float2 a = *(const float2*)(As + kk * 36 + 2 * ty);
                float2 b = *(const float2*)(Bs + kk * 36 + 2 * tx);
                acc00 = fmaf(a.x, b.x, acc00);
                acc01 = fmaf(a.x, b.y, acc01);
                acc10 = fmaf(a.y, b.x, acc10);
                acc11 = fmaf(a.y, b.y, acc11);
            }
        }
        float* c0 = Wf + (size_t)(e0 + 2 * ty) * 512 + k0c + 2 * tx;
        c0[0] = acc00; c0[1] = acc01;
        c0[512] = acc10; c0[513] = acc11;
    }
}

// ---------------- NT GEMM (in-proj): tile 32x64, REP-diagnostic ----------------
__global__ __launch_bounds__(256) void k_gemm_nt32(const float* __restrict__ A,
                                                   const float* __restrict__ Bw,
                                                   float* __restrict__ C,
                                                   int M, int N, int K) {
    __shared__ float As[16][36];
    __shared__ float Bs[16][68];
    int tid = threadIdx.x;
    int tx = tid & 15, ty = tid >> 4;
    int n0 = blockIdx.x * 64;
    int m0 = blockIdx.y * 32;
    int lr = tid >> 2;
    int lk = (tid & 3) * 4;

    for (int rep = 0; rep < REP; ++rep) {
        float acc[2][4];
#pragma unroll
        for (int i = 0; i < 2; ++i)
#pragma unroll
            for (int j = 0; j < 4; ++j) acc[i][j] = 0.0f;

        for (int k0 = 0; k0 < K; k0 += 16) {
            float4 bv = *(const float4*)(Bw + (size_t)(n0 + lr) * K + k0 + lk);
            float4 av;
            if (tid < 128) av = *(const float4*)(A + (size_t)(m0 + lr) * K + k0 + lk);
            __syncthreads();
            Bs[lk + 0][lr] = bv.x; Bs[lk + 1][lr] = bv.y; Bs[lk + 2][lr] = bv.z; Bs[lk + 3][lr] = bv.w;
            if (tid < 128) {
                As[lk + 0][lr] = av.x; As[lk + 1][lr] = av.y; As[lk + 2][lr] = av.z; As[lk + 3][lr] = av.w;
            }
            __syncthreads();
#pragma unroll
            for (int kk = 0; kk < 16; ++kk) {
                float2 a = *(const float2*)(&As[kk][2 * ty]);
                float4 bf = *(const float4*)(&Bs[kk][4 * tx]);
                acc[0][0] = fmaf(a.x, bf.x, acc[0][0]);
                acc[0][1] = fmaf(a.x, bf.y, acc[0][1]);
                acc[0][2] = fmaf(a.x, bf.z, acc[0][2]);
                acc[0][3] = fmaf(a.x, bf.w, acc[0][3]);
                acc[1][0] = fmaf(a.y, bf.x, acc[1][0]);
                acc[1][1] = fmaf(a.y, bf.y, acc[1][1]);
                acc[1][2] = fmaf(a.y, bf.z, acc[1][2]);
                acc[1][3] = fmaf(a.y, bf.w, acc[1][3]);
            }
        }
#pragma unroll
        for (int i = 0; i < 2; ++i) {
            float4 o;
            o.x = acc[i][0]; o.y = acc[i][1]; o.z = acc[i][2]; o.w = acc[i][3];
            *(float4*)(C + (size_t)(m0 + 2 * ty + i) * N + n0 + 4 * tx) = o;
        }
        __syncthreads();
    }
}

// ---------------- TN GEMM 32x64 (transition), REP-diagnostic ----------------
__global__ __launch_bounds__(256) void k_gemm_tn(const float* __restrict__ At,
                                                 const float* __restrict__ B,
                                                 float* __restrict__ C,
                                                 int ldc) {
    __shared__ float As[16 * 36];
    __shared__ float Bs[16 * 68];
    int tid = threadIdx.x;
    int tx = tid & 15, ty = tid >> 4;
    int n0 = blockIdx.x * 64;
    int m0 = blockIdx.y * 32;
    int b = m0 >> 8, l0 = m0 & 255;

    for (int rep = 0; rep < REP; ++rep) {
        float acc[2][4];
#pragma unroll
        for (int i = 0; i < 2; ++i)
#pragma unroll
            for (int j = 0; j < 4; ++j) acc[i][j] = 0.0f;

        for (int d0 = 0; d0 < 512; d0 += 16) {
            float4 va, vb1, vb2;
            if (tid < 128) {
                int r = tid >> 3, q = tid & 7;
                va = *(const float4*)(At + ((size_t)(b * 512 + d0 + r)) * 256 + l0 + 4 * q);
            } else {
                int idx = tid - 128;
                int nr = idx >> 1, q = idx & 1;
                const float* bp = B + (size_t)(n0 + nr) * 512 + d0 + 8 * q;
                vb1 = *(const float4*)(bp);
                vb2 = *(const float4*)(bp + 4);
            }
            __syncthreads();
            if (tid < 128) {
                int r = tid >> 3, q = tid & 7;
                *(float4*)(As + r * 36 + 4 * q) = va;
            } else {
                int idx = tid - 128, nr = idx >> 1, q = idx & 1;
                Bs[(8 * q + 0) * 68 + nr] = vb1.x;
                Bs[(8 * q + 1) * 68 + nr] = vb1.y;
                Bs[(8 * q + 2) * 68 + nr] = vb1.z;
                Bs[(8 * q + 3) * 68 + nr] = vb1.w;
                Bs[(8 * q + 4) * 68 + nr] = vb2.x;
                Bs[(8 * q + 5) * 68 + nr] = vb2.y;
                Bs[(8 * q + 6) * 68 + nr] = vb2.z;
                Bs[(8 * q + 7) * 68 + nr] = vb2.w;
            }
            __syncthreads();
#pragma unroll
            for (int kk = 0; kk < 16; ++kk) {
                float2 a = *(const float2*)(As + kk * 36 + 2 * ty);
                float4 bf = *(const float4*)(Bs + kk * 68 + 4 * tx);
                acc[0][0] = fmaf(a.x, bf.x, acc[0][0]);
                acc[0][1] = fmaf(a.x, bf.y, acc[0][1]);
                acc[0][2] = fmaf(a.x, bf.z, acc[0][2]);
                acc[0][3] = fmaf(a.x, bf.w, acc[0][3]);
                acc[1][0] = fmaf(a.y, bf.x, acc[1][0]);
                acc[1][1] = fmaf(a.y, bf.y, acc[1][1]);
                acc[1][2] = fmaf(a.y, bf.z, acc[1][2]);
                acc[1][3] = fmaf(a.y, bf.w, acc[1][3]);
            }
        }
#pragma unroll
        for (int i = 0; i < 2; ++i) {
            float4 o;
            o.x = acc[i][0]; o.y = acc[i][1]; o.z = acc[i][2]; o.w = acc[i][3];
            *(float4*)(C + (size_t)(m0 + 2 * ty + i) * ldc + n0 + 4 * tx) = o;
        }
        __syncthreads();
    }
}

// ---------------- TN GEMM 32x32 (out-proj), REP-diagnostic ----------------
__global__ __launch_bounds__(256) void k_gemm_tn32(const float* __restrict__ At,
                                                   const float* __restrict__ B,
                                                   float* __restrict__ C,
                                                   int ldc) {
    __shared__ float As[16 * 36];
    __shared__ float Bs[16 * 36];
    int tid = threadIdx.x;
    int tx = tid & 15, ty = tid >> 4;
    int n0 = blockIdx.x * 32;
    int m0 = blockIdx.y * 32;
    int b = m0 >> 8, l0 = m0 & 255;

    for (int rep = 0; rep < REP; ++rep) {
        float acc00 = 0.f, acc01 = 0.f, acc10 = 0.f, acc11 = 0.f;
        for (int d0 = 0; d0 < 512; d0 += 16) {
            float4 v;
            if (tid < 128) {
                int r = tid >> 3, q = tid & 7;
                v = *(const float4*)(At + ((size_t)(b * 512 + d0 + r)) * 256 + l0 + 4 * q);
            } else {
                int idx = tid - 128;
                int nr = idx >> 2, q = idx & 3;
                v = *(const float4*)(B + (size_t)(n0 + nr) * 512 + d0 + 4 * q);
            }
            __syncthreads();
            if (tid < 128) {
                int r = tid >> 3, q = tid & 7;
                *(float4*)(As + r * 36 + 4 * q) = v;
            } else {
                int idx = tid - 128;
                int nr = idx >> 2, q = idx & 3;
                Bs[(4 * q + 0) * 36 + nr] = v.x;
                Bs[(4 * q + 1) * 36 + nr] = v.y;
                Bs[(4 * q + 2) * 36 + nr] = v.z;
                Bs[(4 * q + 3) * 36 + nr] = v.w;
            }
            __syncthreads();
#pragma unroll
            for (int kk = 0; kk < 16; ++kk) {
                float2 a = *(const float2*)(As + kk * 36 + 2 * ty);
                float2 bb = *(const float2*)(Bs + kk * 36 + 2 * tx);
                acc00 = fmaf(a.x, bb.x, acc00);
                acc01 = fmaf(a.x, bb.y, acc01);
                acc10 = fmaf(a.y, bb.x, acc10);
                acc11 = fmaf(a.y, bb.y, acc11);
            }
        }
        float2 o0; o0.x = acc00; o0.y = acc01;
        float2 o1; o1.x = acc10; o1.y = acc11;
        *(float2*)(C + (size_t)(m0 + 2 * ty + 0) * ldc + n0 + 2 * tx) = o0;
        *(float2*)(C + (size_t)(m0 + 2 * ty + 1) * ldc + n0 + 2 * tx) = o1;
        __syncthreads();
    }
}

// ---------------- fused conv+silu+xproj, REP-diagnostic ----------------
__global__ __launch_bounds__(256) void k_mid(const float* __restrict__ xz,
                                             const float* __restrict__ cw,
                                             const float* __restrict__ cb,
                                             const float* __restrict__ xpw,
                                             float* __restrict__ xx,
                                             float* __restrict__ xdbl) {
    __shared__ float xs[DI];
    __shared__ float pr[256];
    int bl = blockIdx.x;
    int b = bl >> 8, l = bl & 255;
    int tid = threadIdx.x;

    for (int rep = 0; rep < REP; ++rep) {
        __syncthreads();   // guard WAR on xs/pr from previous rep
#pragma unroll
        for (int c = 0; c < 2; ++c) {
            int d = tid + 256 * c;
            float4 w4 = *(const float4*)(cw + d * 4);
            float acc = cb[d];
#pragma unroll
            for (int k = 0; k < 4; ++k) {
                int ls = l + k - 3;
                float v = (ls >= 0) ? xz[((size_t)(b * LL + ls)) * 1024 + d] : 0.0f;
                acc = fmaf(((const float*)&w4)[k], v, acc);
            }
            float v = acc / (1.0f + expf(-acc));
            xs[d] = v;
            xx[(size_t)bl * DI + d] = v;
        }
        __syncthreads();

        int e = tid >> 2, c2 = tid & 3;
        float a = 0.0f;
        if (e < 48) {
            const float4* xv4 = (const float4*)(xs + c2 * 128);
            const float4* wv4 = (const float4*)(xpw + (size_t)e * DI + c2 * 128);
#pragma unroll 8
            for (int q = 0; q < 32; ++q) {
                float4 x4 = xv4[q], p4 = wv4[q];
                a = fmaf(x4.x, p4.x, a);
                a = fmaf(x4.y, p4.y, a);
                a = fmaf(x4.z, p4.z, a);
                a = fmaf(x4.w, p4.w, a);
            }
        }
        pr[tid] = a;
        __syncthreads();
        if (tid < 48)
            xdbl[(size_t)bl * 48 + tid] = pr[4 * tid] + pr[4 * tid + 1] + pr[4 * tid + 2] + pr[4 * tid + 3];
    }
}

// ---------------- selective scan, REP-diagnostic ----------------
__global__ __launch_bounds__(256) void k_scan(const float* __restrict__ xx,
                                              const float* __restrict__ xdbl,
                                              const float* __restrict__ xz,
                                              const float* __restrict__ Alog,
                                              const float* __restrict__ Dp,
                                              const float* __restrict__ dtw,
                                              const float* __restrict__ dtb,
                                              float* __restrict__ ygT) {
    __shared__ float yred[4][LL];
    __shared__ float us[LL];
    int tid = threadIdx.x;
    int lane = tid & 63, w = tid >> 6;
    int seq = blockIdx.x;
    int d = seq & (DI - 1), b = seq >> 9;
    int l0 = lane * 4;

    for (int rep = 0; rep < REP; ++rep) {
        __syncthreads();   // guard WAR on us/yred from previous rep
        const float* xd0 = xdbl + ((size_t)(b * LL) + l0) * 48;
        const float* wr = dtw + d * 16;
        float4 w0 = *(const float4*)(wr + 0);
        float4 w1 = *(const float4*)(wr + 4);
        float4 w2 = *(const float4*)(wr + 8);
        float4 w3 = *(const float4*)(wr + 12);
        float bias = dtb[d];

        float dt[4], u[4], dtu[4], P[4];
#pragma unroll
        for (int i = 0; i < 4; ++i) {
            const float* xr = xd0 + i * 48;
            float4 a0 = *(const float4*)(xr + 0);
            float4 a1 = *(const float4*)(xr + 4);
            float4 a2 = *(const float4*)(xr + 8);
            float4 a3 = *(const float4*)(xr + 12);
            float acc = bias;
            acc = fmaf(a0.x, w0.x, acc); acc = fmaf(a0.y, w0.y, acc);
            acc = fmaf(a0.z, w0.z, acc); acc = fmaf(a0.w, w0.w, acc);
            acc = fmaf(a1.x, w1.x, acc); acc = fmaf(a1.y, w1.y, acc);
            acc = fmaf(a1.z, w1.z, acc); acc = fmaf(a1.w, w1.w, acc);
            acc = fmaf(a2.x, w2.x, acc); acc = fmaf(a2.y, w2.y, acc);
            acc = fmaf(a2.z, w2.z, acc); acc = fmaf(a2.w, w2.w, acc);
            acc = fmaf(a3.x, w3.x, acc); acc = fmaf(a3.y, w3.y, acc);
            acc = fmaf(a3.z, w3.z, acc); acc = fmaf(a3.w, w3.w, acc);
            dt[i] = (acc > 20.0f) ? acc : log1pf(expf(acc));
            u[i] = xx[((size_t)(b * LL) + l0 + i) * DI + d];
            dtu[i] = dt[i] * u[i];
        }

        P[0] = dt[0]; P[1] = P[0] + dt[1]; P[2] = P[1] + dt[2]; P[3] = P[2] + dt[3];
        float s = P[3];
#pragma unroll
        for (int off = 1; off < 64; off <<= 1) {
            float t = __shfl_up(s, off);
            if (lane >= off) s += t;
        }
        float base = s - P[3];
        float dt_end = __shfl(s, 63);
        float Dtc[4];
#pragma unroll
        for (int i = 0; i < 4; ++i) Dtc[i] = P[i] + base;

        if (w == 0) {
#pragma unroll
            for (int i = 0; i < 4; ++i) us[l0 + i] = u[i];
        }

        float4 Al = *(const float4*)(Alog + d * 16 + 4 * w);
        float A[4] = {-expf(Al.x), -expf(Al.y), -expf(Al.z), -expf(Al.w)};
        float Bv[4][4], Cv[4][4];
#pragma unroll
        for (int i = 0; i < 4; ++i) {
            float4 bq = *(const float4*)(xd0 + i * 48 + 16 + 4 * w);
            float4 cq = *(const float4*)(xd0 + i * 48 + 32 + 4 * w);
            Bv[i][0] = bq.x; Bv[i][1] = bq.y; Bv[i][2] = bq.z; Bv[i][3] = bq.w;
            Cv[i][0] = cq.x; Cv[i][1] = cq.y; Cv[i][2] = cq.z; Cv[i][3] = cq.w;
        }

        float y[4] = {0.f, 0.f, 0.f, 0.f};
#pragma unroll
        for (int c = 0; c < 4; ++c) {
            float Ac = A[c];
            float dAc[4], t[4];
#pragma unroll
            for (int i = 0; i < 4; ++i) {
                dAc[i] = expf(Ac * (dt_end - Dtc[i]));
                t[i] = dtu[i] * Bv[i][c] * dAc[i];
            }
            float p0 = t[0], p1 = p0 + t[1], p2 = p1 + t[2], p3 = p2 + t[3];
            float ss = p3;
#pragma unroll
            for (int off = 1; off < 64; off <<= 1) {
                float tt = __shfl_up(ss, off);
                if (lane >= off) ss += tt;
            }
            float baseT = ss - p3;
            y[0] += (p0 + baseT) / (dAc[0] + 1e-12f) * Cv[0][c];
            y[1] += (p1 + baseT) / (dAc[1] + 1e-12f) * Cv[1][c];
            y[2] += (p2 + baseT) / (dAc[2] + 1e-12f) * Cv[2][c];
            y[3] += (p3 + baseT) / (dAc[3] + 1e-12f) * Cv[3][c];
        }
#pragma unroll
        for (int i = 0; i < 4; ++i) yred[w][l0 + i] = y[i];
        __syncthreads();

        int l = tid;
        float ysum = yred[0][l] + yred[1][l] + yred[2][l] + yred[3][l];
        float yv = fmaf(us[l], Dp[d], ysum);
        float res = xz[((size_t)(b * LL) + l) * 1024 + DI + d];
        ygT[(size_t)seq * LL + l] = yv * (res / (1.0f + expf(-res)));
    }
}

// ---------------- phase C ----------------
__global__ __launch_bounds__(256) void k_fuse_mean_h(const float* __restrict__ m,
                                                     const float* __restrict__ x0,
                                                     float* __restrict__ xw) {
    int bd = blockIdx.x;
    int b = bd >> 8, d = bd & 255;
    int w = threadIdx.x;
    __shared__ float ms[LL];
    ms[w] = m[((size_t)(b * LL) + w) * DM + d];
    __syncthreads();
    const float* xrow = x0 + (size_t)bd * 65536;
    float a0 = 0.0f, a1 = 0.0f, a2 = 0.0f, a3 = 0.0f;
    for (int h = 0; h < 256; h += 8) {
        float xv[8];
#pragma unroll
        for (int j = 0; j < 8; ++j) xv[j] = xrow[(size_t)(h + j) * 256 + w];
        a0 = fmaf(ms[h + 0], xv[0], a0);
        a1 = fmaf(ms[h + 1], xv[1], a1);
        a2 = fmaf(ms[h + 2], xv[2], a2);
        a3 = fmaf(ms[h + 3], xv[3], a3);
        a0 = fmaf(ms[h + 4], xv[4], a0);
        a1 = fmaf(ms[h + 5], xv[5], a1);
        a2 = fmaf(ms[h + 6], xv[6], a2);
        a3 = fmaf(ms[h + 7], xv[7], a3);
    }
    float acc = (a0 + a1) + (a2 + a3);
    xw[((size_t)(b * LL) + w) * DM + d] = acc * (1.0f / 256.0f);
}

// ---------------- phase E ----------------
__global__ __launch_bounds__(256) void k_final(const float* __restrict__ mw,
                                               const float* __restrict__ x0,
                                               float* __restrict__ out) {
    __shared__ float ms[LL];
    int bd = blockIdx.x;
    int b = bd >> 8, d = bd & 255;
    int tid = threadIdx.x;
    ms[tid] = mw[((size_t)(b * LL) + tid) * DM + d];
    __syncthreads();

    int w4 = tid & 63;
    int hq = tid >> 6;
    float4 mv = *(const float4*)(ms + (w4 << 2));
    const float4* xin = (const float4*)(x0 + (size_t)bd * 65536);
    float4* oout = (float4*)(out + (size_t)bd * 65536);
#pragma unroll 4
    for (int hi = 0; hi < 64; ++hi) {
        int h = hi * 4 + hq;
        size_t idx = (size_t)h * 64 + w4;
        float4 xv = xin[idx];
        float4 o;
        o.x = mv.x * xv.x;
        o.y = mv.y * xv.y;
        o.z = mv.z * xv.z;
        o.w = mv.w * xv.w;
        oout[idx] = o;
    }
}

extern "C" void kernel_launch(void* const* d_in, const int* in_sizes, int n_in,
                              void* d_out, int out_size, void* d_ws, size_t ws_size,
                              hipStream_t stream) {
    const float* x0      = (const float*)d_in[0];
    const float* in_w    = (const float*)d_in[1];
    const float* conv_w  = (const float*)d_in[2];
    const float* conv_b  = (const float*)d_in[3];
    const float* xproj_w = (const float*)d_in[4];
    const float* dt_w    = (const float*)d_in[5];
    const float* dt_b    = (const float*)d_in[6];
    const float* A_log   = (const float*)d_in[7];
    const float* Dp      = (const float*)d_in[8];
    const float* out_w   = (const float*)d_in[9];
    float* out = (float*)d_out;

    float* S0   = (float*)d_ws;
    float* Sout = S0 + 262144;
    float* Wf   = Sout + 262144;
    float* xz   = Wf + 524288;
    float* xx   = xz + 1048576;
    float* xdbl = xx + 524288;
    float* ygT  = xdbl + 49152;

    const float* out_w1 = out_w + 131072;

    auto run_model = [&](const float* inb, float* outb) {
        k_gemm_nt32<<<dim3(16, 32), 256, 0, stream>>>(inb, in_w, xz, NBL, 1024, 256);
        k_mid<<<NBL, 256, 0, stream>>>(xz, conv_w, conv_b, xproj_w, xx, xdbl);
        k_scan<<<BSZ * DI, 256, 0, stream>>>(xx, xdbl, xz, A_log, Dp, dt_w, dt_b, ygT);
        k_gemm_tn<<<dim3(16, 32), 256, 0, stream>>>(ygT, Wf, xz, 1024);
        k_mid<<<NBL, 256, 0, stream>>>(xz, conv_w + 2048, conv_b + 512,
                                       xproj_w + 24576, xx, xdbl);
        k_scan<<<BSZ * DI, 256, 0, stream>>>(xx, xdbl, xz, A_log + 8192, Dp + 512,
                                             dt_w + 8192, dt_b + 512, ygT);
        k_gemm_tn32<<<dim3(8, 32), 256, 0, stream>>>(ygT, out_w1, outb, 256);
    };

    k_meanw_prep<<<1536, 256, 0, stream>>>(x0, in_w + 262144, out_w, S0, Wf);
    run_model(S0, Sout);
    k_fuse_mean_h<<<NBL, 256, 0, stream>>>(Sout, x0, S0);
    run_model(S0, Sout);
    k_final<<<NBL, 256, 0, stream>>>(Sout, x0, out);
}

// Round 10
// 508.444 us; speedup vs baseline: 3.6660x; 3.6660x over previous
//
#include <hip/hip_runtime.h>
#include <math.h>

#define BSZ 4
#define DM 256
#define LL 256
#define DI 512
#define NBL (BSZ * LL)  // 1024

// XCD batch-locality swizzle: launch index j -> (batch b, intra-batch i)
// ensures j%8 == 2b + (i&1), so batch b lands on XCD pair {2b, 2b+1}
__device__ __forceinline__ void unswz(int j, int& b, int& i) {
    b = (j & 7) >> 1;
    i = ((j >> 3) << 1) | (j & 1);
}

// ---------------- dispatch 1: mean over W (blocks 0..1023, swizzled) + Wf prep ----------------
__global__ __launch_bounds__(256) void k_meanw_prep(const float* __restrict__ x0,
                                                    const float* __restrict__ in_w1,
                                                    const float* __restrict__ out_w0,
                                                    float* __restrict__ S0,
                                                    float* __restrict__ Wf) {
    __shared__ float smem[1664];
    int bl = blockIdx.x;
    int tid = threadIdx.x;
    if (bl < 1024) {
        int b, i; unswz(bl, b, i);           // i = d-chunk index (0..255)
        int rowblk = (b << 8) | i;           // row-block in (b,d) space
        int wv = tid >> 6, lane = tid & 63;
        const float4* x4 = (const float4*)x0;
        int rbase = rowblk * 256 + wv * 64;
        for (int i0 = 0; i0 < 64; i0 += 4) {
            float s[4];
#pragma unroll
            for (int j = 0; j < 4; ++j) {
                float4 v = x4[(size_t)(rbase + i0 + j) * 64 + lane];
                s[j] = (v.x + v.y) + (v.z + v.w);
            }
#pragma unroll
            for (int j = 0; j < 4; ++j) {
#pragma unroll
                for (int m = 32; m >= 1; m >>= 1) s[j] += __shfl_xor(s[j], m);
            }
            if (lane == 0) {
#pragma unroll
                for (int j = 0; j < 4; ++j) {
                    int rr = rbase + i0 + j;
                    int bb = rr >> 16, d = (rr >> 8) & 255, h = rr & 255;
                    S0[((size_t)(bb * LL) + h) * DM + d] = s[j] * (1.0f / 256.0f);
                }
            }
        }
    } else {
        float* As = smem;
        float* Bs = smem + 576;
        int t = bl - 1024;
        int e0 = (t >> 4) * 32, k0c = (t & 15) * 32;
        int tx = tid & 15, ty = tid >> 4;
        float acc00 = 0.f, acc01 = 0.f, acc10 = 0.f, acc11 = 0.f;
        for (int dm0 = 0; dm0 < 256; dm0 += 16) {
            float4 v;
            if (tid < 128) {
                int r = tid >> 2, q = tid & 3;
                v = *(const float4*)(in_w1 + (size_t)(e0 + r) * 256 + dm0 + 4 * q);
            } else {
                int idx = tid - 128;
                int r = idx >> 3, q = idx & 7;
                v = *(const float4*)(out_w0 + (size_t)(dm0 + r) * 512 + k0c + 4 * q);
            }
            __syncthreads();
            if (tid < 128) {
                int r = tid >> 2, q = tid & 3;
                As[(4 * q + 0) * 36 + r] = v.x;
                As[(4 * q + 1) * 36 + r] = v.y;
                As[(4 * q + 2) * 36 + r] = v.z;
                As[(4 * q + 3) * 36 + r] = v.w;
            } else {
                int idx = tid - 128;
                int r = idx >> 3, q = idx & 7;
                Bs[r * 36 + 4 * q + 0] = v.x;
                Bs[r * 36 + 4 * q + 1] = v.y;
                Bs[r * 36 + 4 * q + 2] = v.z;
                Bs[r * 36 + 4 * q + 3] = v.w;
            }
            __syncthreads();
#pragma unroll
            for (int kk = 0; kk < 16; ++kk) {
                float2 a = *(const float2*)(As + kk * 36 + 2 * ty);
                float2 b2 = *(const float2*)(Bs + kk * 36 + 2 * tx);
                acc00 = fmaf(a.x, b2.x, acc00);
                acc01 = fmaf(a.x, b2.y, acc01);
                acc10 = fmaf(a.y, b2.x, acc10);
                acc11 = fmaf(a.y, b2.y, acc11);
            }
        }
        float* c0 = Wf + (size_t)(e0 + 2 * ty) * 512 + k0c + 2 * tx;
        c0[0] = acc00; c0[1] = acc01;
        c0[512] = acc10; c0[513] = acc11;
    }
}

// ---------------- in-proj GEMM: 64x64 tile, 4x4 micro, K=256, grid 256 ----------------
// C[(b,l)][e] = sum_k S0[(b,l)][k] * in_w[e][k]
__global__ __launch_bounds__(256) void k_gemm_nt64(const float* __restrict__ A,
                                                   const float* __restrict__ Bw,
                                                   float* __restrict__ C) {
    __shared__ float As[16][68];
    __shared__ float Bs[16][68];
    int tid = threadIdx.x;
    int b, i; unswz(blockIdx.x, b, i);
    int m0 = b * 256 + (i >> 4) * 64;
    int n0 = (i & 15) * 64;
    int tx = tid & 15, ty = tid >> 4;
    int r = tid >> 2, kq = (tid & 3) * 4;

    const float* pa = A + (size_t)(m0 + r) * 256 + kq;
    const float* pb = Bw + (size_t)(n0 + r) * 256 + kq;
    float4 ra = *(const float4*)pa;
    float4 rb = *(const float4*)pb;

    float acc[4][4];
#pragma unroll
    for (int ii = 0; ii < 4; ++ii)
#pragma unroll
        for (int jj = 0; jj < 4; ++jj) acc[ii][jj] = 0.0f;

    for (int k0 = 0; k0 < 256; k0 += 16) {
        __syncthreads();
        As[kq + 0][r] = ra.x; As[kq + 1][r] = ra.y; As[kq + 2][r] = ra.z; As[kq + 3][r] = ra.w;
        Bs[kq + 0][r] = rb.x; Bs[kq + 1][r] = rb.y; Bs[kq + 2][r] = rb.z; Bs[kq + 3][r] = rb.w;
        __syncthreads();
        if (k0 + 16 < 256) {
            ra = *(const float4*)(pa + k0 + 16);
            rb = *(const float4*)(pb + k0 + 16);
        }
#pragma unroll
        for (int kk = 0; kk < 16; ++kk) {
            float4 a4 = *(const float4*)(&As[kk][ty * 4]);
            float4 b4 = *(const float4*)(&Bs[kk][tx * 4]);
            float aa[4] = {a4.x, a4.y, a4.z, a4.w};
            float bb[4] = {b4.x, b4.y, b4.z, b4.w};
#pragma unroll
            for (int ii = 0; ii < 4; ++ii)
#pragma unroll
                for (int jj = 0; jj < 4; ++jj)
                    acc[ii][jj] = fmaf(aa[ii], bb[jj], acc[ii][jj]);
        }
    }
#pragma unroll
    for (int ii = 0; ii < 4; ++ii) {
        float4 o;
        o.x = acc[ii][0]; o.y = acc[ii][1]; o.z = acc[ii][2]; o.w = acc[ii][3];
        *(float4*)(C + (size_t)(m0 + ty * 4 + ii) * 1024 + n0 + tx * 4) = o;
    }
}

// ---------------- transition GEMM: 64x64 tile, 4x4 micro, K=512, grid 256 ----------------
// C[(b,l)][e] = sum_d ygT[(b*512+d)*256+l] * Wf[e*512+d]
__global__ __launch_bounds__(256) void k_gemm_tn64(const float* __restrict__ At,
                                                   const float* __restrict__ Bw,
                                                   float* __restrict__ C) {
    __shared__ float As[16][68];
    __shared__ float Bs[16][68];
    int tid = threadIdx.x;
    int b, i; unswz(blockIdx.x, b, i);
    int l0 = (i >> 4) * 64;
    int n0 = (i & 15) * 64;
    int m0 = b * 256 + l0;
    int tx = tid & 15, ty = tid >> 4;
    int rkk = tid >> 4, mq = (tid & 15) * 4;   // A-stage: row kk, col chunk
    int rn = tid >> 2, dq = (tid & 3) * 4;     // B-stage: row n, k chunk

    const float* pa = At + ((size_t)(b * 512) + rkk) * 256 + l0 + mq;
    const float* pb = Bw + (size_t)(n0 + rn) * 512 + dq;
    float4 ra = *(const float4*)pa;
    float4 rb = *(const float4*)pb;

    float acc[4][4];
#pragma unroll
    for (int ii = 0; ii < 4; ++ii)
#pragma unroll
        for (int jj = 0; jj < 4; ++jj) acc[ii][jj] = 0.0f;

    for (int d0 = 0; d0 < 512; d0 += 16) {
        __syncthreads();
        *(float4*)(&As[rkk][mq]) = ra;
        Bs[dq + 0][rn] = rb.x; Bs[dq + 1][rn] = rb.y; Bs[dq + 2][rn] = rb.z; Bs[dq + 3][rn] = rb.w;
        __syncthreads();
        if (d0 + 16 < 512) {
            ra = *(const float4*)(pa + (size_t)(d0 + 16) * 256);
            rb = *(const float4*)(pb + d0 + 16);
        }
#pragma unroll
        for (int kk = 0; kk < 16; ++kk) {
            float4 a4 = *(const float4*)(&As[kk][ty * 4]);
            float4 b4 = *(const float4*)(&Bs[kk][tx * 4]);
            float aa[4] = {a4.x, a4.y, a4.z, a4.w};
            float bb[4] = {b4.x, b4.y, b4.z, b4.w};
#pragma unroll
            for (int ii = 0; ii < 4; ++ii)
#pragma unroll
                for (int jj = 0; jj < 4; ++jj)
                    acc[ii][jj] = fmaf(aa[ii], bb[jj], acc[ii][jj]);
        }
    }
#pragma unroll
    for (int ii = 0; ii < 4; ++ii) {
        float4 o;
        o.x = acc[ii][0]; o.y = acc[ii][1]; o.z = acc[ii][2]; o.w = acc[ii][3];
        *(float4*)(C + (size_t)(m0 + ty * 4 + ii) * 1024 + n0 + tx * 4) = o;
    }
}

// ---------------- out-proj TN GEMM 32x32 (N=256), grid 256, swizzled ----------------
__global__ __launch_bounds__(256) void k_gemm_tn32(const float* __restrict__ At,
                                                   const float* __restrict__ B,
                                                   float* __restrict__ C) {
    __shared__ float As[16 * 36];
    __shared__ float Bs[16 * 36];
    int tid = threadIdx.x;
    int tx = tid & 15, ty = tid >> 4;
    int b, i; unswz(blockIdx.x, b, i);
    int l0 = (i >> 3) * 32;
    int n0 = (i & 7) * 32;
    int m0 = b * 256 + l0;

    float acc00 = 0.f, acc01 = 0.f, acc10 = 0.f, acc11 = 0.f;
    for (int d0 = 0; d0 < 512; d0 += 16) {
        float4 v;
        if (tid < 128) {
            int r = tid >> 3, q = tid & 7;
            v = *(const float4*)(At + ((size_t)(b * 512 + d0 + r)) * 256 + l0 + 4 * q);
        } else {
            int idx = tid - 128;
            int nr = idx >> 2, q = idx & 3;
            v = *(const float4*)(B + (size_t)(n0 + nr) * 512 + d0 + 4 * q);
        }
        __syncthreads();
        if (tid < 128) {
            int r = tid >> 3, q = tid & 7;
            *(float4*)(As + r * 36 + 4 * q) = v;
        } else {
            int idx = tid - 128;
            int nr = idx >> 2, q = idx & 3;
            Bs[(4 * q + 0) * 36 + nr] = v.x;
            Bs[(4 * q + 1) * 36 + nr] = v.y;
            Bs[(4 * q + 2) * 36 + nr] = v.z;
            Bs[(4 * q + 3) * 36 + nr] = v.w;
        }
        __syncthreads();
#pragma unroll
        for (int kk = 0; kk < 16; ++kk) {
            float2 a = *(const float2*)(As + kk * 36 + 2 * ty);
            float2 bb = *(const float2*)(Bs + kk * 36 + 2 * tx);
            acc00 = fmaf(a.x, bb.x, acc00);
            acc01 = fmaf(a.x, bb.y, acc01);
            acc10 = fmaf(a.y, bb.x, acc10);
            acc11 = fmaf(a.y, bb.y, acc11);
        }
    }
    float2 o0; o0.x = acc00; o0.y = acc01;
    float2 o1; o1.x = acc10; o1.y = acc11;
    *(float2*)(C + (size_t)(m0 + 2 * ty + 0) * 256 + n0 + 2 * tx) = o0;
    *(float2*)(C + (size_t)(m0 + 2 * ty + 1) * 256 + n0 + 2 * tx) = o1;
}

// ---------------- fused conv+silu+xproj: one block per (b,l), swizzled ----------------
__global__ __launch_bounds__(256) void k_mid(const float* __restrict__ xz,
                                             const float* __restrict__ cw,
                                             const float* __restrict__ cb,
                                             const float* __restrict__ xpw,
                                             float* __restrict__ xx,
                                             float* __restrict__ xdbl) {
    __shared__ float xs[DI];
    __shared__ float pr[256];
    int b, l; unswz(blockIdx.x, b, l);
    int bl = (b << 8) | l;
    int tid = threadIdx.x;

#pragma unroll
    for (int c = 0; c < 2; ++c) {
        int d = tid + 256 * c;
        float4 w4 = *(const float4*)(cw + d * 4);
        float acc = cb[d];
#pragma unroll
        for (int k = 0; k < 4; ++k) {
            int ls = l + k - 3;
            float v = (ls >= 0) ? xz[((size_t)(b * LL + ls)) * 1024 + d] : 0.0f;
            acc = fmaf(((const float*)&w4)[k], v, acc);
        }
        float v = acc / (1.0f + expf(-acc));
        xs[d] = v;
        xx[(size_t)bl * DI + d] = v;
    }
    __syncthreads();

    int e = tid >> 2, c2 = tid & 3;
    float a = 0.0f;
    if (e < 48) {
        const float4* xv4 = (const float4*)(xs + c2 * 128);
        const float4* wv4 = (const float4*)(xpw + (size_t)e * DI + c2 * 128);
#pragma unroll 8
        for (int q = 0; q < 32; ++q) {
            float4 x4 = xv4[q], p4 = wv4[q];
            a = fmaf(x4.x, p4.x, a);
            a = fmaf(x4.y, p4.y, a);
            a = fmaf(x4.z, p4.z, a);
            a = fmaf(x4.w, p4.w, a);
        }
    }
    pr[tid] = a;
    __syncthreads();
    if (tid < 48)
        xdbl[(size_t)bl * 48 + tid] = pr[4 * tid] + pr[4 * tid + 1] + pr[4 * tid + 2] + pr[4 * tid + 3];
}

// ---------------- selective scan: block per (b,d), swizzled; writes ygT coalesced ----------------
__global__ __launch_bounds__(256) void k_scan(const float* __restrict__ xx,
                                              const float* __restrict__ xdbl,
                                              const float* __restrict__ xz,
                                              const float* __restrict__ Alog,
                                              const float* __restrict__ Dp,
                                              const float* __restrict__ dtw,
                                              const float* __restrict__ dtb,
                                              float* __restrict__ ygT) {
    __shared__ float yred[4][LL];
    __shared__ float us[LL];
    int tid = threadIdx.x;
    int lane = tid & 63, w = tid >> 6;
    int b, d; unswz(blockIdx.x, b, d);
    int seq = b * DI + d;
    int l0 = lane * 4;

    const float* xd0 = xdbl + ((size_t)(b * LL) + l0) * 48;
    const float* wr = dtw + d * 16;
    float4 w0 = *(const float4*)(wr + 0);
    float4 w1 = *(const float4*)(wr + 4);
    float4 w2 = *(const float4*)(wr + 8);
    float4 w3 = *(const float4*)(wr + 12);
    float bias = dtb[d];

    float dt[4], u[4], dtu[4], P[4];
#pragma unroll
    for (int i = 0; i < 4; ++i) {
        const float* xr = xd0 + i * 48;
        float4 a0 = *(const float4*)(xr + 0);
        float4 a1 = *(const float4*)(xr + 4);
        float4 a2 = *(const float4*)(xr + 8);
        float4 a3 = *(const float4*)(xr + 12);
        float acc = bias;
        acc = fmaf(a0.x, w0.x, acc); acc = fmaf(a0.y, w0.y, acc);
        acc = fmaf(a0.z, w0.z, acc); acc = fmaf(a0.w, w0.w, acc);
        acc = fmaf(a1.x, w1.x, acc); acc = fmaf(a1.y, w1.y, acc);
        acc = fmaf(a1.z, w1.z, acc); acc = fmaf(a1.w, w1.w, acc);
        acc = fmaf(a2.x, w2.x, acc); acc = fmaf(a2.y, w2.y, acc);
        acc = fmaf(a2.z, w2.z, acc); acc = fmaf(a2.w, w2.w, acc);
        acc = fmaf(a3.x, w3.x, acc); acc = fmaf(a3.y, w3.y, acc);
        acc = fmaf(a3.z, w3.z, acc); acc = fmaf(a3.w, w3.w, acc);
        dt[i] = (acc > 20.0f) ? acc : log1pf(expf(acc));
        u[i] = xx[((size_t)(b * LL) + l0 + i) * DI + d];
        dtu[i] = dt[i] * u[i];
    }

    P[0] = dt[0]; P[1] = P[0] + dt[1]; P[2] = P[1] + dt[2]; P[3] = P[2] + dt[3];
    float s = P[3];
#pragma unroll
    for (int off = 1; off < 64; off <<= 1) {
        float t = __shfl_up(s, off);
        if (lane >= off) s += t;
    }
    float base = s - P[3];
    float dt_end = __shfl(s, 63);
    float Dtc[4];
#pragma unroll
    for (int i = 0; i < 4; ++i) Dtc[i] = P[i] + base;

    if (w == 0) {
#pragma unroll
        for (int i = 0; i < 4; ++i) us[l0 + i] = u[i];
    }

    float4 Al = *(const float4*)(Alog + d * 16 + 4 * w);
    float A[4] = {-expf(Al.x), -expf(Al.y), -expf(Al.z), -expf(Al.w)};
    float Bv[4][4], Cv[4][4];
#pragma unroll
    for (int i = 0; i < 4; ++i) {
        float4 bq = *(const float4*)(xd0 + i * 48 + 16 + 4 * w);
        float4 cq = *(const float4*)(xd0 + i * 48 + 32 + 4 * w);
        Bv[i][0] = bq.x; Bv[i][1] = bq.y; Bv[i][2] = bq.z; Bv[i][3] = bq.w;
        Cv[i][0] = cq.x; Cv[i][1] = cq.y; Cv[i][2] = cq.z; Cv[i][3] = cq.w;
    }

    float y[4] = {0.f, 0.f, 0.f, 0.f};
#pragma unroll
    for (int c = 0; c < 4; ++c) {
        float Ac = A[c];
        float dAc[4], t[4];
#pragma unroll
        for (int i = 0; i < 4; ++i) {
            dAc[i] = expf(Ac * (dt_end - Dtc[i]));
            t[i] = dtu[i] * Bv[i][c] * dAc[i];
        }
        float p0 = t[0], p1 = p0 + t[1], p2 = p1 + t[2], p3 = p2 + t[3];
        float ss = p3;
#pragma unroll
        for (int off = 1; off < 64; off <<= 1) {
            float tt = __shfl_up(ss, off);
            if (lane >= off) ss += tt;
        }
        float baseT = ss - p3;
        y[0] += (p0 + baseT) / (dAc[0] + 1e-12f) * Cv[0][c];
        y[1] += (p1 + baseT) / (dAc[1] + 1e-12f) * Cv[1][c];
        y[2] += (p2 + baseT) / (dAc[2] + 1e-12f) * Cv[2][c];
        y[3] += (p3 + baseT) / (dAc[3] + 1e-12f) * Cv[3][c];
    }
#pragma unroll
    for (int i = 0; i < 4; ++i) yred[w][l0 + i] = y[i];
    __syncthreads();

    int l = tid;
    float ysum = yred[0][l] + yred[1][l] + yred[2][l] + yred[3][l];
    float yv = fmaf(us[l], Dp[d], ysum);
    float res = xz[((size_t)(b * LL) + l) * 1024 + DI + d];
    ygT[(size_t)seq * LL + l] = yv * (res / (1.0f + expf(-res)));
}

// ---------------- phase C: swizzled ----------------
__global__ __launch_bounds__(256) void k_fuse_mean_h(const float* __restrict__ m,
                                                     const float* __restrict__ x0,
                                                     float* __restrict__ xw) {
    int b, d; unswz(blockIdx.x, b, d);
    int bd = (b << 8) | d;
    int w = threadIdx.x;
    __shared__ float ms[LL];
    ms[w] = m[((size_t)(b * LL) + w) * DM + d];
    __syncthreads();
    const float* xrow = x0 + (size_t)bd * 65536;
    float a0 = 0.0f, a1 = 0.0f, a2 = 0.0f, a3 = 0.0f;
    for (int h = 0; h < 256; h += 8) {
        float xv[8];
#pragma unroll
        for (int j = 0; j < 8; ++j) xv[j] = xrow[(size_t)(h + j) * 256 + w];
        a0 = fmaf(ms[h + 0], xv[0], a0);
        a1 = fmaf(ms[h + 1], xv[1], a1);
        a2 = fmaf(ms[h + 2], xv[2], a2);
        a3 = fmaf(ms[h + 3], xv[3], a3);
        a0 = fmaf(ms[h + 4], xv[4], a0);
        a1 = fmaf(ms[h + 5], xv[5], a1);
        a2 = fmaf(ms[h + 6], xv[6], a2);
        a3 = fmaf(ms[h + 7], xv[7], a3);
    }
    float acc = (a0 + a1) + (a2 + a3);
    xw[((size_t)(b * LL) + w) * DM + d] = acc * (1.0f / 256.0f);
}

// ---------------- phase E: swizzled ----------------
__global__ __launch_bounds__(256) void k_final(const float* __restrict__ mw,
                                               const float* __restrict__ x0,
                                               float* __restrict__ out) {
    __shared__ float ms[LL];
    int b, d; unswz(blockIdx.x, b, d);
    int bd = (b << 8) | d;
    int tid = threadIdx.x;
    ms[tid] = mw[((size_t)(b * LL) + tid) * DM + d];
    __syncthreads();

    int w4 = tid & 63;
    int hq = tid >> 6;
    float4 mv = *(const float4*)(ms + (w4 << 2));
    const float4* xin = (const float4*)(x0 + (size_t)bd * 65536);
    float4* oout = (float4*)(out + (size_t)bd * 65536);
#pragma unroll 4
    for (int hi = 0; hi < 64; ++hi) {
        int h = hi * 4 + hq;
        size_t idx = (size_t)h * 64 + w4;
        float4 xv = xin[idx];
        float4 o;
        o.x = mv.x * xv.x;
        o.y = mv.y * xv.y;
        o.z = mv.z * xv.z;
        o.w = mv.w * xv.w;
        oout[idx] = o;
    }
}

extern "C" void kernel_launch(void* const* d_in, const int* in_sizes, int n_in,
                              void* d_out, int out_size, void* d_ws, size_t ws_size,
                              hipStream_t stream) {
    const float* x0      = (const float*)d_in[0];
    const float* in_w    = (const float*)d_in[1];
    const float* conv_w  = (const float*)d_in[2];
    const float* conv_b  = (const float*)d_in[3];
    const float* xproj_w = (const float*)d_in[4];
    const float* dt_w    = (const float*)d_in[5];
    const float* dt_b    = (const float*)d_in[6];
    const float* A_log   = (const float*)d_in[7];
    const float* Dp      = (const float*)d_in[8];
    const float* out_w   = (const float*)d_in[9];
    float* out = (float*)d_out;

    float* S0   = (float*)d_ws;
    float* Sout = S0 + 262144;
    float* Wf   = Sout + 262144;
    float* xz   = Wf + 524288;
    float* xx   = xz + 1048576;
    float* xdbl = xx + 524288;
    float* ygT  = xdbl + 49152;

    const float* out_w1 = out_w + 131072;

    auto run_model = [&](const float* inb, float* outb) {
        k_gemm_nt64<<<256, 256, 0, stream>>>(inb, in_w, xz);
        k_mid<<<NBL, 256, 0, stream>>>(xz, conv_w, conv_b, xproj_w, xx, xdbl);
        k_scan<<<BSZ * DI, 256, 0, stream>>>(xx, xdbl, xz, A_log, Dp, dt_w, dt_b, ygT);
        k_gemm_tn64<<<256, 256, 0, stream>>>(ygT, Wf, xz);
        k_mid<<<NBL, 256, 0, stream>>>(xz, conv_w + 2048, conv_b + 512,
                                       xproj_w + 24576, xx, xdbl);
        k_scan<<<BSZ * DI, 256, 0, stream>>>(xx, xdbl, xz, A_log + 8192, Dp + 512,
                                             dt_w + 8192, dt_b + 512, ygT);
        k_gemm_tn32<<<256, 256, 0, stream>>>(ygT, out_w1, outb);
    };

    k_meanw_prep<<<1536, 256, 0, stream>>>(x0, in_w + 262144, out_w, S0, Wf);
    run_model(S0, Sout);
    k_fuse_mean_h<<<NBL, 256, 0, stream>>>(Sout, x0, S0);
    run_model(S0, Sout);
    k_final<<<NBL, 256, 0, stream>>>(Sout, x0, out);
}

// Round 11
// 505.408 us; speedup vs baseline: 3.6880x; 1.0060x over previous
//
#include <hip/hip_runtime.h>
#include <math.h>

#define BSZ 4
#define DM 256
#define LL 256
#define DI 512
#define NBL (BSZ * LL)  // 1024

// XCD batch-locality swizzle: launch index j -> (batch b, intra-batch i)
__device__ __forceinline__ void unswz(int j, int& b, int& i) {
    b = (j & 7) >> 1;
    i = ((j >> 3) << 1) | (j & 1);
}

// ---------------- dispatch 1: mean over W (blocks 0..1023, swizzled) + Wf prep ----------------
__global__ __launch_bounds__(256) void k_meanw_prep(const float* __restrict__ x0,
                                                    const float* __restrict__ in_w1,
                                                    const float* __restrict__ out_w0,
                                                    float* __restrict__ S0,
                                                    float* __restrict__ Wf) {
    __shared__ float smem[1664];
    int bl = blockIdx.x;
    int tid = threadIdx.x;
    if (bl < 1024) {
        int b, i; unswz(bl, b, i);
        int rowblk = (b << 8) | i;
        int wv = tid >> 6, lane = tid & 63;
        const float4* x4 = (const float4*)x0;
        int rbase = rowblk * 256 + wv * 64;
        for (int i0 = 0; i0 < 64; i0 += 4) {
            float s[4];
#pragma unroll
            for (int j = 0; j < 4; ++j) {
                float4 v = x4[(size_t)(rbase + i0 + j) * 64 + lane];
                s[j] = (v.x + v.y) + (v.z + v.w);
            }
#pragma unroll
            for (int j = 0; j < 4; ++j) {
#pragma unroll
                for (int m = 32; m >= 1; m >>= 1) s[j] += __shfl_xor(s[j], m);
            }
            if (lane == 0) {
#pragma unroll
                for (int j = 0; j < 4; ++j) {
                    int rr = rbase + i0 + j;
                    int bb = rr >> 16, d = (rr >> 8) & 255, h = rr & 255;
                    S0[((size_t)(bb * LL) + h) * DM + d] = s[j] * (1.0f / 256.0f);
                }
            }
        }
    } else {
        float* As = smem;
        float* Bs = smem + 576;
        int t = bl - 1024;
        int e0 = (t >> 4) * 32, k0c = (t & 15) * 32;
        int tx = tid & 15, ty = tid >> 4;
        float acc00 = 0.f, acc01 = 0.f, acc10 = 0.f, acc11 = 0.f;
        for (int dm0 = 0; dm0 < 256; dm0 += 16) {
            float4 v;
            if (tid < 128) {
                int r = tid >> 2, q = tid & 3;
                v = *(const float4*)(in_w1 + (size_t)(e0 + r) * 256 + dm0 + 4 * q);
            } else {
                int idx = tid - 128;
                int r = idx >> 3, q = idx & 7;
                v = *(const float4*)(out_w0 + (size_t)(dm0 + r) * 512 + k0c + 4 * q);
            }
            __syncthreads();
            if (tid < 128) {
                int r = tid >> 2, q = tid & 3;
                As[(4 * q + 0) * 36 + r] = v.x;
                As[(4 * q + 1) * 36 + r] = v.y;
                As[(4 * q + 2) * 36 + r] = v.z;
                As[(4 * q + 3) * 36 + r] = v.w;
            } else {
                int idx = tid - 128;
                int r = idx >> 3, q = idx & 7;
                Bs[r * 36 + 4 * q + 0] = v.x;
                Bs[r * 36 + 4 * q + 1] = v.y;
                Bs[r * 36 + 4 * q + 2] = v.z;
                Bs[r * 36 + 4 * q + 3] = v.w;
            }
            __syncthreads();
#pragma unroll
            for (int kk = 0; kk < 16; ++kk) {
                float2 a = *(const float2*)(As + kk * 36 + 2 * ty);
                float2 b2 = *(const float2*)(Bs + kk * 36 + 2 * tx);
                acc00 = fmaf(a.x, b2.x, acc00);
                acc01 = fmaf(a.x, b2.y, acc01);
                acc10 = fmaf(a.y, b2.x, acc10);
                acc11 = fmaf(a.y, b2.y, acc11);
            }
        }
        float* c0 = Wf + (size_t)(e0 + 2 * ty) * 512 + k0c + 2 * tx;
        c0[0] = acc00; c0[1] = acc01;
        c0[512] = acc10; c0[513] = acc11;
    }
}

// ---------------- in-proj GEMM: 64x64 tile, 4x4 micro, K=256, grid 256 ----------------
__global__ __launch_bounds__(256) void k_gemm_nt64(const float* __restrict__ A,
                                                   const float* __restrict__ Bw,
                                                   float* __restrict__ C) {
    __shared__ float As[16][68];
    __shared__ float Bs[16][68];
    int tid = threadIdx.x;
    int b, i; unswz(blockIdx.x, b, i);
    int m0 = b * 256 + (i >> 4) * 64;
    int n0 = (i & 15) * 64;
    int tx = tid & 15, ty = tid >> 4;
    int r = tid >> 2, kq = (tid & 3) * 4;

    const float* pa = A + (size_t)(m0 + r) * 256 + kq;
    const float* pb = Bw + (size_t)(n0 + r) * 256 + kq;
    float4 ra = *(const float4*)pa;
    float4 rb = *(const float4*)pb;

    float acc[4][4];
#pragma unroll
    for (int ii = 0; ii < 4; ++ii)
#pragma unroll
        for (int jj = 0; jj < 4; ++jj) acc[ii][jj] = 0.0f;

    for (int k0 = 0; k0 < 256; k0 += 16) {
        __syncthreads();
        As[kq + 0][r] = ra.x; As[kq + 1][r] = ra.y; As[kq + 2][r] = ra.z; As[kq + 3][r] = ra.w;
        Bs[kq + 0][r] = rb.x; Bs[kq + 1][r] = rb.y; Bs[kq + 2][r] = rb.z; Bs[kq + 3][r] = rb.w;
        __syncthreads();
        if (k0 + 16 < 256) {
            ra = *(const float4*)(pa + k0 + 16);
            rb = *(const float4*)(pb + k0 + 16);
        }
#pragma unroll
        for (int kk = 0; kk < 16; ++kk) {
            float4 a4 = *(const float4*)(&As[kk][ty * 4]);
            float4 b4 = *(const float4*)(&Bs[kk][tx * 4]);
            float aa[4] = {a4.x, a4.y, a4.z, a4.w};
            float bb[4] = {b4.x, b4.y, b4.z, b4.w};
#pragma unroll
            for (int ii = 0; ii < 4; ++ii)
#pragma unroll
                for (int jj = 0; jj < 4; ++jj)
                    acc[ii][jj] = fmaf(aa[ii], bb[jj], acc[ii][jj]);
        }
    }
#pragma unroll
    for (int ii = 0; ii < 4; ++ii) {
        float4 o;
        o.x = acc[ii][0]; o.y = acc[ii][1]; o.z = acc[ii][2]; o.w = acc[ii][3];
        *(float4*)(C + (size_t)(m0 + ty * 4 + ii) * 1024 + n0 + tx * 4) = o;
    }
}

// ---------------- transition GEMM: 64x64 tile, 4x4 micro, K=512, grid 256 ----------------
__global__ __launch_bounds__(256) void k_gemm_tn64(const float* __restrict__ At,
                                                   const float* __restrict__ Bw,
                                                   float* __restrict__ C) {
    __shared__ float As[16][68];
    __shared__ float Bs[16][68];
    int tid = threadIdx.x;
    int b, i; unswz(blockIdx.x, b, i);
    int l0 = (i >> 4) * 64;
    int n0 = (i & 15) * 64;
    int m0 = b * 256 + l0;
    int tx = tid & 15, ty = tid >> 4;
    int rkk = tid >> 4, mq = (tid & 15) * 4;
    int rn = tid >> 2, dq = (tid & 3) * 4;

    const float* pa = At + ((size_t)(b * 512) + rkk) * 256 + l0 + mq;
    const float* pb = Bw + (size_t)(n0 + rn) * 512 + dq;
    float4 ra = *(const float4*)pa;
    float4 rb = *(const float4*)pb;

    float acc[4][4];
#pragma unroll
    for (int ii = 0; ii < 4; ++ii)
#pragma unroll
        for (int jj = 0; jj < 4; ++jj) acc[ii][jj] = 0.0f;

    for (int d0 = 0; d0 < 512; d0 += 16) {
        __syncthreads();
        *(float4*)(&As[rkk][mq]) = ra;
        Bs[dq + 0][rn] = rb.x; Bs[dq + 1][rn] = rb.y; Bs[dq + 2][rn] = rb.z; Bs[dq + 3][rn] = rb.w;
        __syncthreads();
        if (d0 + 16 < 512) {
            ra = *(const float4*)(pa + (size_t)(d0 + 16) * 256);
            rb = *(const float4*)(pb + d0 + 16);
        }
#pragma unroll
        for (int kk = 0; kk < 16; ++kk) {
            float4 a4 = *(const float4*)(&As[kk][ty * 4]);
            float4 b4 = *(const float4*)(&Bs[kk][tx * 4]);
            float aa[4] = {a4.x, a4.y, a4.z, a4.w};
            float bb[4] = {b4.x, b4.y, b4.z, b4.w};
#pragma unroll
            for (int ii = 0; ii < 4; ++ii)
#pragma unroll
                for (int jj = 0; jj < 4; ++jj)
                    acc[ii][jj] = fmaf(aa[ii], bb[jj], acc[ii][jj]);
        }
    }
#pragma unroll
    for (int ii = 0; ii < 4; ++ii) {
        float4 o;
        o.x = acc[ii][0]; o.y = acc[ii][1]; o.z = acc[ii][2]; o.w = acc[ii][3];
        *(float4*)(C + (size_t)(m0 + ty * 4 + ii) * 1024 + n0 + tx * 4) = o;
    }
}

// ---------------- out-proj TN GEMM 32x32 (N=256), grid 256, swizzled ----------------
__global__ __launch_bounds__(256) void k_gemm_tn32(const float* __restrict__ At,
                                                   const float* __restrict__ B,
                                                   float* __restrict__ C) {
    __shared__ float As[16 * 36];
    __shared__ float Bs[16 * 36];
    int tid = threadIdx.x;
    int tx = tid & 15, ty = tid >> 4;
    int b, i; unswz(blockIdx.x, b, i);
    int l0 = (i >> 3) * 32;
    int n0 = (i & 7) * 32;
    int m0 = b * 256 + l0;

    float acc00 = 0.f, acc01 = 0.f, acc10 = 0.f, acc11 = 0.f;
    for (int d0 = 0; d0 < 512; d0 += 16) {
        float4 v;
        if (tid < 128) {
            int r = tid >> 3, q = tid & 7;
            v = *(const float4*)(At + ((size_t)(b * 512 + d0 + r)) * 256 + l0 + 4 * q);
        } else {
            int idx = tid - 128;
            int nr = idx >> 2, q = idx & 3;
            v = *(const float4*)(B + (size_t)(n0 + nr) * 512 + d0 + 4 * q);
        }
        __syncthreads();
        if (tid < 128) {
            int r = tid >> 3, q = tid & 7;
            *(float4*)(As + r * 36 + 4 * q) = v;
        } else {
            int idx = tid - 128;
            int nr = idx >> 2, q = idx & 3;
            Bs[(4 * q + 0) * 36 + nr] = v.x;
            Bs[(4 * q + 1) * 36 + nr] = v.y;
            Bs[(4 * q + 2) * 36 + nr] = v.z;
            Bs[(4 * q + 3) * 36 + nr] = v.w;
        }
        __syncthreads();
#pragma unroll
        for (int kk = 0; kk < 16; ++kk) {
            float2 a = *(const float2*)(As + kk * 36 + 2 * ty);
            float2 bb = *(const float2*)(Bs + kk * 36 + 2 * tx);
            acc00 = fmaf(a.x, bb.x, acc00);
            acc01 = fmaf(a.x, bb.y, acc01);
            acc10 = fmaf(a.y, bb.x, acc10);
            acc11 = fmaf(a.y, bb.y, acc11);
        }
    }
    float2 o0; o0.x = acc00; o0.y = acc01;
    float2 o1; o1.x = acc10; o1.y = acc11;
    *(float2*)(C + (size_t)(m0 + 2 * ty + 0) * 256 + n0 + 2 * tx) = o0;
    *(float2*)(C + (size_t)(m0 + 2 * ty + 1) * 256 + n0 + 2 * tx) = o1;
}

// ---------------- fused conv+silu+xproj: 256 blocks x 4 (b,l) each ----------------
__global__ __launch_bounds__(256) void k_mid(const float* __restrict__ xz,
                                             const float* __restrict__ cw,
                                             const float* __restrict__ cb,
                                             const float* __restrict__ xpw,
                                             float* __restrict__ xx,
                                             float* __restrict__ xdbl) {
    __shared__ float xs[DI];
    __shared__ float pr[256];
    int tid = threadIdx.x;
    int b = (blockIdx.x & 7) >> 1;
    int ib = ((blockIdx.x >> 3) << 1) | (blockIdx.x & 1);   // 0..63

    for (int k = 0; k < 4; ++k) {
        int l = ib + 64 * k;
        int bl = (b << 8) | l;
        __syncthreads();   // guard WAR on xs/pr from previous iteration
#pragma unroll
        for (int c = 0; c < 2; ++c) {
            int d = tid + 256 * c;
            float4 w4 = *(const float4*)(cw + d * 4);
            float acc = cb[d];
#pragma unroll
            for (int kk = 0; kk < 4; ++kk) {
                int ls = l + kk - 3;
                float v = (ls >= 0) ? xz[((size_t)(b * LL + ls)) * 1024 + d] : 0.0f;
                acc = fmaf(((const float*)&w4)[kk], v, acc);
            }
            float v = acc / (1.0f + expf(-acc));
            xs[d] = v;
            xx[(size_t)bl * DI + d] = v;
        }
        __syncthreads();

        int e = tid >> 2, c2 = tid & 3;
        float a = 0.0f;
        if (e < 48) {
            const float4* xv4 = (const float4*)(xs + c2 * 128);
            const float4* wv4 = (const float4*)(xpw + (size_t)e * DI + c2 * 128);
#pragma unroll 8
            for (int q = 0; q < 32; ++q) {
                float4 x4 = xv4[q], p4 = wv4[q];
                a = fmaf(x4.x, p4.x, a);
                a = fmaf(x4.y, p4.y, a);
                a = fmaf(x4.z, p4.z, a);
                a = fmaf(x4.w, p4.w, a);
            }
        }
        pr[tid] = a;
        __syncthreads();
        if (tid < 48)
            xdbl[(size_t)bl * 48 + tid] = pr[4 * tid] + pr[4 * tid + 1] + pr[4 * tid + 2] + pr[4 * tid + 3];
    }
}

// ---------------- selective scan: 512 blocks x 4 sequences each ----------------
__global__ __launch_bounds__(256) void k_scan(const float* __restrict__ xx,
                                              const float* __restrict__ xdbl,
                                              const float* __restrict__ xz,
                                              const float* __restrict__ Alog,
                                              const float* __restrict__ Dp,
                                              const float* __restrict__ dtw,
                                              const float* __restrict__ dtb,
                                              float* __restrict__ ygT) {
    __shared__ float yred[4][LL];
    __shared__ float us[LL];
    int tid = threadIdx.x;
    int lane = tid & 63, w = tid >> 6;
    int b = (blockIdx.x & 7) >> 1;
    int ib = ((blockIdx.x >> 3) << 1) | (blockIdx.x & 1);   // 0..127
    int l0 = lane * 4;

    for (int kq = 0; kq < 4; ++kq) {
        int d = ib + 128 * kq;
        int seq = b * DI + d;
        __syncthreads();   // guard WAR on us/yred from previous iteration

        const float* xd0 = xdbl + ((size_t)(b * LL) + l0) * 48;
        const float* wr = dtw + d * 16;
        float4 w0 = *(const float4*)(wr + 0);
        float4 w1 = *(const float4*)(wr + 4);
        float4 w2 = *(const float4*)(wr + 8);
        float4 w3 = *(const float4*)(wr + 12);
        float bias = dtb[d];

        float dt[4], u[4], dtu[4], P[4];
#pragma unroll
        for (int i = 0; i < 4; ++i) {
            const float* xr = xd0 + i * 48;
            float4 a0 = *(const float4*)(xr + 0);
            float4 a1 = *(const float4*)(xr + 4);
            float4 a2 = *(const float4*)(xr + 8);
            float4 a3 = *(const float4*)(xr + 12);
            float acc = bias;
            acc = fmaf(a0.x, w0.x, acc); acc = fmaf(a0.y, w0.y, acc);
            acc = fmaf(a0.z, w0.z, acc); acc = fmaf(a0.w, w0.w, acc);
            acc = fmaf(a1.x, w1.x, acc); acc = fmaf(a1.y, w1.y, acc);
            acc = fmaf(a1.z, w1.z, acc); acc = fmaf(a1.w, w1.w, acc);
            acc = fmaf(a2.x, w2.x, acc); acc = fmaf(a2.y, w2.y, acc);
            acc = fmaf(a2.z, w2.z, acc); acc = fmaf(a2.w, w2.w, acc);
            acc = fmaf(a3.x, w3.x, acc); acc = fmaf(a3.y, w3.y, acc);
            acc = fmaf(a3.z, w3.z, acc); acc = fmaf(a3.w, w3.w, acc);
            dt[i] = (acc > 20.0f) ? acc : log1pf(expf(acc));
            u[i] = xx[((size_t)(b * LL) + l0 + i) * DI + d];
            dtu[i] = dt[i] * u[i];
        }

        P[0] = dt[0]; P[1] = P[0] + dt[1]; P[2] = P[1] + dt[2]; P[3] = P[2] + dt[3];
        float s = P[3];
#pragma unroll
        for (int off = 1; off < 64; off <<= 1) {
            float t = __shfl_up(s, off);
            if (lane >= off) s += t;
        }
        float base = s - P[3];
        float dt_end = __shfl(s, 63);
        float Dtc[4];
#pragma unroll
        for (int i = 0; i < 4; ++i) Dtc[i] = P[i] + base;

        if (w == 0) {
#pragma unroll
            for (int i = 0; i < 4; ++i) us[l0 + i] = u[i];
        }

        float4 Al = *(const float4*)(Alog + d * 16 + 4 * w);
        float A[4] = {-expf(Al.x), -expf(Al.y), -expf(Al.z), -expf(Al.w)};
        float Bv[4][4], Cv[4][4];
#pragma unroll
        for (int i = 0; i < 4; ++i) {
            float4 bq = *(const float4*)(xd0 + i * 48 + 16 + 4 * w);
            float4 cq = *(const float4*)(xd0 + i * 48 + 32 + 4 * w);
            Bv[i][0] = bq.x; Bv[i][1] = bq.y; Bv[i][2] = bq.z; Bv[i][3] = bq.w;
            Cv[i][0] = cq.x; Cv[i][1] = cq.y; Cv[i][2] = cq.z; Cv[i][3] = cq.w;
        }

        float y[4] = {0.f, 0.f, 0.f, 0.f};
#pragma unroll
        for (int c = 0; c < 4; ++c) {
            float Ac = A[c];
            float dAc[4], t[4];
#pragma unroll
            for (int i = 0; i < 4; ++i) {
                dAc[i] = expf(Ac * (dt_end - Dtc[i]));
                t[i] = dtu[i] * Bv[i][c] * dAc[i];
            }
            float p0 = t[0], p1 = p0 + t[1], p2 = p1 + t[2], p3 = p2 + t[3];
            float ss = p3;
#pragma unroll
            for (int off = 1; off < 64; off <<= 1) {
                float tt = __shfl_up(ss, off);
                if (lane >= off) ss += tt;
            }
            float baseT = ss - p3;
            y[0] += (p0 + baseT) / (dAc[0] + 1e-12f) * Cv[0][c];
            y[1] += (p1 + baseT) / (dAc[1] + 1e-12f) * Cv[1][c];
            y[2] += (p2 + baseT) / (dAc[2] + 1e-12f) * Cv[2][c];
            y[3] += (p3 + baseT) / (dAc[3] + 1e-12f) * Cv[3][c];
        }
#pragma unroll
        for (int i = 0; i < 4; ++i) yred[w][l0 + i] = y[i];
        __syncthreads();

        int l = tid;
        float ysum = yred[0][l] + yred[1][l] + yred[2][l] + yred[3][l];
        float yv = fmaf(us[l], Dp[d], ysum);
        float res = xz[((size_t)(b * LL) + l) * 1024 + DI + d];
        ygT[(size_t)seq * LL + l] = yv * (res / (1.0f + expf(-res)));
    }
}

// ---------------- phase C: swizzled ----------------
__global__ __launch_bounds__(256) void k_fuse_mean_h(const float* __restrict__ m,
                                                     const float* __restrict__ x0,
                                                     float* __restrict__ xw) {
    int b, d; unswz(blockIdx.x, b, d);
    int bd = (b << 8) | d;
    int w = threadIdx.x;
    __shared__ float ms[LL];
    ms[w] = m[((size_t)(b * LL) + w) * DM + d];
    __syncthreads();
    const float* xrow = x0 + (size_t)bd * 65536;
    float a0 = 0.0f, a1 = 0.0f, a2 = 0.0f, a3 = 0.0f;
    for (int h = 0; h < 256; h += 8) {
        float xv[8];
#pragma unroll
        for (int j = 0; j < 8; ++j) xv[j] = xrow[(size_t)(h + j) * 256 + w];
        a0 = fmaf(ms[h + 0], xv[0], a0);
        a1 = fmaf(ms[h + 1], xv[1], a1);
        a2 = fmaf(ms[h + 2], xv[2], a2);
        a3 = fmaf(ms[h + 3], xv[3], a3);
        a0 = fmaf(ms[h + 4], xv[4], a0);
        a1 = fmaf(ms[h + 5], xv[5], a1);
        a2 = fmaf(ms[h + 6], xv[6], a2);
        a3 = fmaf(ms[h + 7], xv[7], a3);
    }
    float acc = (a0 + a1) + (a2 + a3);
    xw[((size_t)(b * LL) + w) * DM + d] = acc * (1.0f / 256.0f);
}

// ---------------- phase E: swizzled ----------------
__global__ __launch_bounds__(256) void k_final(const float* __restrict__ mw,
                                               const float* __restrict__ x0,
                                               float* __restrict__ out) {
    __shared__ float ms[LL];
    int b, d; unswz(blockIdx.x, b, d);
    int bd = (b << 8) | d;
    int tid = threadIdx.x;
    ms[tid] = mw[((size_t)(b * LL) + tid) * DM + d];
    __syncthreads();

    int w4 = tid & 63;
    int hq = tid >> 6;
    float4 mv = *(const float4*)(ms + (w4 << 2));
    const float4* xin = (const float4*)(x0 + (size_t)bd * 65536);
    float4* oout = (float4*)(out + (size_t)bd * 65536);
#pragma unroll 4
    for (int hi = 0; hi < 64; ++hi) {
        int h = hi * 4 + hq;
        size_t idx = (size_t)h * 64 + w4;
        float4 xv = xin[idx];
        float4 o;
        o.x = mv.x * xv.x;
        o.y = mv.y * xv.y;
        o.z = mv.z * xv.z;
        o.w = mv.w * xv.w;
        oout[idx] = o;
    }
}

extern "C" void kernel_launch(void* const* d_in, const int* in_sizes, int n_in,
                              void* d_out, int out_size, void* d_ws, size_t ws_size,
                              hipStream_t stream) {
    const float* x0      = (const float*)d_in[0];
    const float* in_w    = (const float*)d_in[1];
    const float* conv_w  = (const float*)d_in[2];
    const float* conv_b  = (const float*)d_in[3];
    const float* xproj_w = (const float*)d_in[4];
    const float* dt_w    = (const float*)d_in[5];
    const float* dt_b    = (const float*)d_in[6];
    const float* A_log   = (const float*)d_in[7];
    const float* Dp      = (const float*)d_in[8];
    const float* out_w   = (const float*)d_in[9];
    float* out = (float*)d_out;

    float* S0   = (float*)d_ws;
    float* Sout = S0 + 262144;
    float* Wf   = Sout + 262144;
    float* xz   = Wf + 524288;
    float* xx   = xz + 1048576;
    float* xdbl = xx + 524288;
    float* ygT  = xdbl + 49152;

    const float* out_w1 = out_w + 131072;

    auto run_model = [&](const float* inb, float* outb) {
        k_gemm_nt64<<<256, 256, 0, stream>>>(inb, in_w, xz);
        k_mid<<<256, 256, 0, stream>>>(xz, conv_w, conv_b, xproj_w, xx, xdbl);
        k_scan<<<512, 256, 0, stream>>>(xx, xdbl, xz, A_log, Dp, dt_w, dt_b, ygT);
        k_gemm_tn64<<<256, 256, 0, stream>>>(ygT, Wf, xz);
        k_mid<<<256, 256, 0, stream>>>(xz, conv_w + 2048, conv_b + 512,
                                       xproj_w + 24576, xx, xdbl);
        k_scan<<<512, 256, 0, stream>>>(xx, xdbl, xz, A_log + 8192, Dp + 512,
                                        dt_w + 8192, dt_b + 512, ygT);
        k_gemm_tn32<<<256, 256, 0, stream>>>(ygT, out_w1, outb);
    };

    k_meanw_prep<<<1536, 256, 0, stream>>>(x0, in_w + 262144, out_w, S0, Wf);
    run_model(S0, Sout);
    k_fuse_mean_h<<<NBL, 256, 0, stream>>>(Sout, x0, S0);
    run_model(S0, Sout);
    k_final<<<NBL, 256, 0, stream>>>(Sout, x0, out);
}

// Round 12
// 479.013 us; speedup vs baseline: 3.8912x; 1.0551x over previous
//
#include <hip/hip_runtime.h>
#include <math.h>

#define BSZ 4
#define DM 256
#define LL 256
#define DI 512
#define NBL (BSZ * LL)  // 1024

__device__ __forceinline__ float fast_rcp(float x) { return __builtin_amdgcn_rcpf(x); }
__device__ __forceinline__ float fast_sig(float x) { return fast_rcp(1.0f + __expf(-x)); }

// XCD batch-locality swizzle: launch index j -> (batch b, intra-batch i)
__device__ __forceinline__ void unswz(int j, int& b, int& i) {
    b = (j & 7) >> 1;
    i = ((j >> 3) << 1) | (j & 1);
}

// ---------------- dispatch 1: mean over W (blocks 0..1023, swizzled) + Wf prep ----------------
__global__ __launch_bounds__(256) void k_meanw_prep(const float* __restrict__ x0,
                                                    const float* __restrict__ in_w1,
                                                    const float* __restrict__ out_w0,
                                                    float* __restrict__ S0,
                                                    float* __restrict__ Wf) {
    __shared__ float smem[1664];
    int bl = blockIdx.x;
    int tid = threadIdx.x;
    if (bl < 1024) {
        int b, i; unswz(bl, b, i);
        int rowblk = (b << 8) | i;
        int wv = tid >> 6, lane = tid & 63;
        const float4* x4 = (const float4*)x0;
        int rbase = rowblk * 256 + wv * 64;
        for (int i0 = 0; i0 < 64; i0 += 8) {
            float s[8];
#pragma unroll
            for (int j = 0; j < 8; ++j) {
                float4 v = x4[(size_t)(rbase + i0 + j) * 64 + lane];
                s[j] = (v.x + v.y) + (v.z + v.w);
            }
#pragma unroll
            for (int j = 0; j < 8; ++j) {
#pragma unroll
                for (int m = 32; m >= 1; m >>= 1) s[j] += __shfl_xor(s[j], m);
            }
            if (lane == 0) {
#pragma unroll
                for (int j = 0; j < 8; ++j) {
                    int rr = rbase + i0 + j;
                    int bb = rr >> 16, d = (rr >> 8) & 255, h = rr & 255;
                    S0[((size_t)(bb * LL) + h) * DM + d] = s[j] * (1.0f / 256.0f);
                }
            }
        }
    } else {
        float* As = smem;
        float* Bs = smem + 576;
        int t = bl - 1024;
        int e0 = (t >> 4) * 32, k0c = (t & 15) * 32;
        int tx = tid & 15, ty = tid >> 4;
        float acc00 = 0.f, acc01 = 0.f, acc10 = 0.f, acc11 = 0.f;
        for (int dm0 = 0; dm0 < 256; dm0 += 16) {
            float4 v;
            if (tid < 128) {
                int r = tid >> 2, q = tid & 3;
                v = *(const float4*)(in_w1 + (size_t)(e0 + r) * 256 + dm0 + 4 * q);
            } else {
                int idx = tid - 128;
                int r = idx >> 3, q = idx & 7;
                v = *(const float4*)(out_w0 + (size_t)(dm0 + r) * 512 + k0c + 4 * q);
            }
            __syncthreads();
            if (tid < 128) {
                int r = tid >> 2, q = tid & 3;
                As[(4 * q + 0) * 36 + r] = v.x;
                As[(4 * q + 1) * 36 + r] = v.y;
                As[(4 * q + 2) * 36 + r] = v.z;
                As[(4 * q + 3) * 36 + r] = v.w;
            } else {
                int idx = tid - 128;
                int r = idx >> 3, q = idx & 7;
                Bs[r * 36 + 4 * q + 0] = v.x;
                Bs[r * 36 + 4 * q + 1] = v.y;
                Bs[r * 36 + 4 * q + 2] = v.z;
                Bs[r * 36 + 4 * q + 3] = v.w;
            }
            __syncthreads();
#pragma unroll
            for (int kk = 0; kk < 16; ++kk) {
                float2 a = *(const float2*)(As + kk * 36 + 2 * ty);
                float2 b2 = *(const float2*)(Bs + kk * 36 + 2 * tx);
                acc00 = fmaf(a.x, b2.x, acc00);
                acc01 = fmaf(a.x, b2.y, acc01);
                acc10 = fmaf(a.y, b2.x, acc10);
                acc11 = fmaf(a.y, b2.y, acc11);
            }
        }
        float* c0 = Wf + (size_t)(e0 + 2 * ty) * 512 + k0c + 2 * tx;
        c0[0] = acc00; c0[1] = acc01;
        c0[512] = acc10; c0[513] = acc11;
    }
}

// ---------------- in-proj GEMM: 64x64 tile, 4x4 micro, K=256, grid 256 ----------------
__global__ __launch_bounds__(256) void k_gemm_nt64(const float* __restrict__ A,
                                                   const float* __restrict__ Bw,
                                                   float* __restrict__ C) {
    __shared__ float As[16][68];
    __shared__ float Bs[16][68];
    int tid = threadIdx.x;
    int b, i; unswz(blockIdx.x, b, i);
    int m0 = b * 256 + (i >> 4) * 64;
    int n0 = (i & 15) * 64;
    int tx = tid & 15, ty = tid >> 4;
    int r = tid >> 2, kq = (tid & 3) * 4;

    const float* pa = A + (size_t)(m0 + r) * 256 + kq;
    const float* pb = Bw + (size_t)(n0 + r) * 256 + kq;
    float4 ra = *(const float4*)pa;
    float4 rb = *(const float4*)pb;

    float acc[4][4];
#pragma unroll
    for (int ii = 0; ii < 4; ++ii)
#pragma unroll
        for (int jj = 0; jj < 4; ++jj) acc[ii][jj] = 0.0f;

    for (int k0 = 0; k0 < 256; k0 += 16) {
        __syncthreads();
        As[kq + 0][r] = ra.x; As[kq + 1][r] = ra.y; As[kq + 2][r] = ra.z; As[kq + 3][r] = ra.w;
        Bs[kq + 0][r] = rb.x; Bs[kq + 1][r] = rb.y; Bs[kq + 2][r] = rb.z; Bs[kq + 3][r] = rb.w;
        __syncthreads();
        if (k0 + 16 < 256) {
            ra = *(const float4*)(pa + k0 + 16);
            rb = *(const float4*)(pb + k0 + 16);
        }
#pragma unroll
        for (int kk = 0; kk < 16; ++kk) {
            float4 a4 = *(const float4*)(&As[kk][ty * 4]);
            float4 b4 = *(const float4*)(&Bs[kk][tx * 4]);
            float aa[4] = {a4.x, a4.y, a4.z, a4.w};
            float bb[4] = {b4.x, b4.y, b4.z, b4.w};
#pragma unroll
            for (int ii = 0; ii < 4; ++ii)
#pragma unroll
                for (int jj = 0; jj < 4; ++jj)
                    acc[ii][jj] = fmaf(aa[ii], bb[jj], acc[ii][jj]);
        }
    }
#pragma unroll
    for (int ii = 0; ii < 4; ++ii) {
        float4 o;
        o.x = acc[ii][0]; o.y = acc[ii][1]; o.z = acc[ii][2]; o.w = acc[ii][3];
        *(float4*)(C + (size_t)(m0 + ty * 4 + ii) * 1024 + n0 + tx * 4) = o;
    }
}

// ---------------- transition GEMM: 64x64 tile, 4x4 micro, K=512, grid 256 ----------------
__global__ __launch_bounds__(256) void k_gemm_tn64(const float* __restrict__ At,
                                                   const float* __restrict__ Bw,
                                                   float* __restrict__ C) {
    __shared__ float As[16][68];
    __shared__ float Bs[16][68];
    int tid = threadIdx.x;
    int b, i; unswz(blockIdx.x, b, i);
    int l0 = (i >> 4) * 64;
    int n0 = (i & 15) * 64;
    int m0 = b * 256 + l0;
    int tx = tid & 15, ty = tid >> 4;
    int rkk = tid >> 4, mq = (tid & 15) * 4;
    int rn = tid >> 2, dq = (tid & 3) * 4;

    const float* pa = At + ((size_t)(b * 512) + rkk) * 256 + l0 + mq;
    const float* pb = Bw + (size_t)(n0 + rn) * 512 + dq;
    float4 ra = *(const float4*)pa;
    float4 rb = *(const float4*)pb;

    float acc[4][4];
#pragma unroll
    for (int ii = 0; ii < 4; ++ii)
#pragma unroll
        for (int jj = 0; jj < 4; ++jj) acc[ii][jj] = 0.0f;

    for (int d0 = 0; d0 < 512; d0 += 16) {
        __syncthreads();
        *(float4*)(&As[rkk][mq]) = ra;
        Bs[dq + 0][rn] = rb.x; Bs[dq + 1][rn] = rb.y; Bs[dq + 2][rn] = rb.z; Bs[dq + 3][rn] = rb.w;
        __syncthreads();
        if (d0 + 16 < 512) {
            ra = *(const float4*)(pa + (size_t)(d0 + 16) * 256);
            rb = *(const float4*)(pb + d0 + 16);
        }
#pragma unroll
        for (int kk = 0; kk < 16; ++kk) {
            float4 a4 = *(const float4*)(&As[kk][ty * 4]);
            float4 b4 = *(const float4*)(&Bs[kk][tx * 4]);
            float aa[4] = {a4.x, a4.y, a4.z, a4.w};
            float bb[4] = {b4.x, b4.y, b4.z, b4.w};
#pragma unroll
            for (int ii = 0; ii < 4; ++ii)
#pragma unroll
                for (int jj = 0; jj < 4; ++jj)
                    acc[ii][jj] = fmaf(aa[ii], bb[jj], acc[ii][jj]);
        }
    }
#pragma unroll
    for (int ii = 0; ii < 4; ++ii) {
        float4 o;
        o.x = acc[ii][0]; o.y = acc[ii][1]; o.z = acc[ii][2]; o.w = acc[ii][3];
        *(float4*)(C + (size_t)(m0 + ty * 4 + ii) * 1024 + n0 + tx * 4) = o;
    }
}

// ---------------- out-proj TN GEMM 32x32 (N=256), grid 256, swizzled ----------------
__global__ __launch_bounds__(256) void k_gemm_tn32(const float* __restrict__ At,
                                                   const float* __restrict__ B,
                                                   float* __restrict__ C) {
    __shared__ float As[16 * 36];
    __shared__ float Bs[16 * 36];
    int tid = threadIdx.x;
    int tx = tid & 15, ty = tid >> 4;
    int b, i; unswz(blockIdx.x, b, i);
    int l0 = (i >> 3) * 32;
    int n0 = (i & 7) * 32;
    int m0 = b * 256 + l0;

    float acc00 = 0.f, acc01 = 0.f, acc10 = 0.f, acc11 = 0.f;
    for (int d0 = 0; d0 < 512; d0 += 16) {
        float4 v;
        if (tid < 128) {
            int r = tid >> 3, q = tid & 7;
            v = *(const float4*)(At + ((size_t)(b * 512 + d0 + r)) * 256 + l0 + 4 * q);
        } else {
            int idx = tid - 128;
            int nr = idx >> 2, q = idx & 3;
            v = *(const float4*)(B + (size_t)(n0 + nr) * 512 + d0 + 4 * q);
        }
        __syncthreads();
        if (tid < 128) {
            int r = tid >> 3, q = tid & 7;
            *(float4*)(As + r * 36 + 4 * q) = v;
        } else {
            int idx = tid - 128;
            int nr = idx >> 2, q = idx & 3;
            Bs[(4 * q + 0) * 36 + nr] = v.x;
            Bs[(4 * q + 1) * 36 + nr] = v.y;
            Bs[(4 * q + 2) * 36 + nr] = v.z;
            Bs[(4 * q + 3) * 36 + nr] = v.w;
        }
        __syncthreads();
#pragma unroll
        for (int kk = 0; kk < 16; ++kk) {
            float2 a = *(const float2*)(As + kk * 36 + 2 * ty);
            float2 bb = *(const float2*)(Bs + kk * 36 + 2 * tx);
            acc00 = fmaf(a.x, bb.x, acc00);
            acc01 = fmaf(a.x, bb.y, acc01);
            acc10 = fmaf(a.y, bb.x, acc10);
            acc11 = fmaf(a.y, bb.y, acc11);
        }
    }
    float2 o0; o0.x = acc00; o0.y = acc01;
    float2 o1; o1.x = acc10; o1.y = acc11;
    *(float2*)(C + (size_t)(m0 + 2 * ty + 0) * 256 + n0 + 2 * tx) = o0;
    *(float2*)(C + (size_t)(m0 + 2 * ty + 1) * 256 + n0 + 2 * tx) = o1;
}

// ---------------- fused conv+silu+xproj: 256 blocks x 4 (b,l) each ----------------
__global__ __launch_bounds__(256) void k_mid(const float* __restrict__ xz,
                                             const float* __restrict__ cw,
                                             const float* __restrict__ cb,
                                             const float* __restrict__ xpw,
                                             float* __restrict__ xx,
                                             float* __restrict__ xdbl) {
    __shared__ float xs[DI];
    __shared__ float pr[256];
    int tid = threadIdx.x;
    int b = (blockIdx.x & 7) >> 1;
    int ib = ((blockIdx.x >> 3) << 1) | (blockIdx.x & 1);   // 0..63

    for (int k = 0; k < 4; ++k) {
        int l = ib + 64 * k;
        int bl = (b << 8) | l;
        __syncthreads();
#pragma unroll
        for (int c = 0; c < 2; ++c) {
            int d = tid + 256 * c;
            float4 w4 = *(const float4*)(cw + d * 4);
            float acc = cb[d];
#pragma unroll
            for (int kk = 0; kk < 4; ++kk) {
                int ls = l + kk - 3;
                float v = (ls >= 0) ? xz[((size_t)(b * LL + ls)) * 1024 + d] : 0.0f;
                acc = fmaf(((const float*)&w4)[kk], v, acc);
            }
            float v = acc * fast_sig(acc);
            xs[d] = v;
            xx[(size_t)bl * DI + d] = v;
        }
        __syncthreads();

        int e = tid >> 2, c2 = tid & 3;
        float a = 0.0f;
        if (e < 48) {
            const float4* xv4 = (const float4*)(xs + c2 * 128);
            const float4* wv4 = (const float4*)(xpw + (size_t)e * DI + c2 * 128);
#pragma unroll 8
            for (int q = 0; q < 32; ++q) {
                float4 x4 = xv4[q], p4 = wv4[q];
                a = fmaf(x4.x, p4.x, a);
                a = fmaf(x4.y, p4.y, a);
                a = fmaf(x4.z, p4.z, a);
                a = fmaf(x4.w, p4.w, a);
            }
        }
        pr[tid] = a;
        __syncthreads();
        if (tid < 48)
            xdbl[(size_t)bl * 48 + tid] = pr[4 * tid] + pr[4 * tid + 1] + pr[4 * tid + 2] + pr[4 * tid + 3];
    }
}

// ---------------- selective scan: 512 blocks x 4 sequences each ----------------
__global__ __launch_bounds__(256) void k_scan(const float* __restrict__ xx,
                                              const float* __restrict__ xdbl,
                                              const float* __restrict__ xz,
                                              const float* __restrict__ Alog,
                                              const float* __restrict__ Dp,
                                              const float* __restrict__ dtw,
                                              const float* __restrict__ dtb,
                                              float* __restrict__ ygT) {
    __shared__ float yred[4][LL];
    __shared__ float us[LL];
    int tid = threadIdx.x;
    int lane = tid & 63, w = tid >> 6;
    int b = (blockIdx.x & 7) >> 1;
    int ib = ((blockIdx.x >> 3) << 1) | (blockIdx.x & 1);   // 0..127
    int l0 = lane * 4;

    for (int kq = 0; kq < 4; ++kq) {
        int d = ib + 128 * kq;
        int seq = b * DI + d;
        __syncthreads();

        const float* xd0 = xdbl + ((size_t)(b * LL) + l0) * 48;
        const float* wr = dtw + d * 16;
        float4 w0 = *(const float4*)(wr + 0);
        float4 w1 = *(const float4*)(wr + 4);
        float4 w2 = *(const float4*)(wr + 8);
        float4 w3 = *(const float4*)(wr + 12);
        float bias = dtb[d];

        float dt[4], u[4], dtu[4], P[4];
#pragma unroll
        for (int i = 0; i < 4; ++i) {
            const float* xr = xd0 + i * 48;
            float4 a0 = *(const float4*)(xr + 0);
            float4 a1 = *(const float4*)(xr + 4);
            float4 a2 = *(const float4*)(xr + 8);
            float4 a3 = *(const float4*)(xr + 12);
            float acc = bias;
            acc = fmaf(a0.x, w0.x, acc); acc = fmaf(a0.y, w0.y, acc);
            acc = fmaf(a0.z, w0.z, acc); acc = fmaf(a0.w, w0.w, acc);
            acc = fmaf(a1.x, w1.x, acc); acc = fmaf(a1.y, w1.y, acc);
            acc = fmaf(a1.z, w1.z, acc); acc = fmaf(a1.w, w1.w, acc);
            acc = fmaf(a2.x, w2.x, acc); acc = fmaf(a2.y, w2.y, acc);
            acc = fmaf(a2.z, w2.z, acc); acc = fmaf(a2.w, w2.w, acc);
            acc = fmaf(a3.x, w3.x, acc); acc = fmaf(a3.y, w3.y, acc);
            acc = fmaf(a3.z, w3.z, acc); acc = fmaf(a3.w, w3.w, acc);
            // softplus via fast exp/log (guard for large x)
            dt[i] = (acc > 20.0f) ? acc : __logf(1.0f + __expf(acc));
            u[i] = xx[((size_t)(b * LL) + l0 + i) * DI + d];
            dtu[i] = dt[i] * u[i];
        }

        P[0] = dt[0]; P[1] = P[0] + dt[1]; P[2] = P[1] + dt[2]; P[3] = P[2] + dt[3];
        float s = P[3];
#pragma unroll
        for (int off = 1; off < 64; off <<= 1) {
            float t = __shfl_up(s, off);
            if (lane >= off) s += t;
        }
        float base = s - P[3];
        float dt_end = __shfl(s, 63);
        float Dtc[4];
#pragma unroll
        for (int i = 0; i < 4; ++i) Dtc[i] = P[i] + base;

        if (w == 0) {
#pragma unroll
            for (int i = 0; i < 4; ++i) us[l0 + i] = u[i];
        }

        float4 Al = *(const float4*)(Alog + d * 16 + 4 * w);
        float A[4] = {-__expf(Al.x), -__expf(Al.y), -__expf(Al.z), -__expf(Al.w)};
        float Bv[4][4], Cv[4][4];
#pragma unroll
        for (int i = 0; i < 4; ++i) {
            float4 bq = *(const float4*)(xd0 + i * 48 + 16 + 4 * w);
            float4 cq = *(const float4*)(xd0 + i * 48 + 32 + 4 * w);
            Bv[i][0] = bq.x; Bv[i][1] = bq.y; Bv[i][2] = bq.z; Bv[i][3] = bq.w;
            Cv[i][0] = cq.x; Cv[i][1] = cq.y; Cv[i][2] = cq.z; Cv[i][3] = cq.w;
        }

        float y[4] = {0.f, 0.f, 0.f, 0.f};
#pragma unroll
        for (int c = 0; c < 4; ++c) {
            float Ac = A[c];
            float dAc[4], t[4];
#pragma unroll
            for (int i = 0; i < 4; ++i) {
                dAc[i] = __expf(Ac * (dt_end - Dtc[i]));
                t[i] = dtu[i] * Bv[i][c] * dAc[i];
            }
            float p0 = t[0], p1 = p0 + t[1], p2 = p1 + t[2], p3 = p2 + t[3];
            float ss = p3;
#pragma unroll
            for (int off = 1; off < 64; off <<= 1) {
                float tt = __shfl_up(ss, off);
                if (lane >= off) ss += tt;
            }
            float baseT = ss - p3;
            y[0] = fmaf((p0 + baseT) * fast_rcp(dAc[0] + 1e-12f), Cv[0][c], y[0]);
            y[1] = fmaf((p1 + baseT) * fast_rcp(dAc[1] + 1e-12f), Cv[1][c], y[1]);
            y[2] = fmaf((p2 + baseT) * fast_rcp(dAc[2] + 1e-12f), Cv[2][c], y[2]);
            y[3] = fmaf((p3 + baseT) * fast_rcp(dAc[3] + 1e-12f), Cv[3][c], y[3]);
        }
#pragma unroll
        for (int i = 0; i < 4; ++i) yred[w][l0 + i] = y[i];
        __syncthreads();

        int l = tid;
        float ysum = yred[0][l] + yred[1][l] + yred[2][l] + yred[3][l];
        float yv = fmaf(us[l], Dp[d], ysum);
        float res = xz[((size_t)(b * LL) + l) * 1024 + DI + d];
        ygT[(size_t)seq * LL + l] = yv * res * fast_sig(res);
    }
}

// ---------------- phase C: swizzled ----------------
__global__ __launch_bounds__(256) void k_fuse_mean_h(const float* __restrict__ m,
                                                     const float* __restrict__ x0,
                                                     float* __restrict__ xw) {
    int b, d; unswz(blockIdx.x, b, d);
    int bd = (b << 8) | d;
    int w = threadIdx.x;
    __shared__ float ms[LL];
    ms[w] = m[((size_t)(b * LL) + w) * DM + d];
    __syncthreads();
    const float* xrow = x0 + (size_t)bd * 65536;
    float a0 = 0.0f, a1 = 0.0f, a2 = 0.0f, a3 = 0.0f;
    for (int h = 0; h < 256; h += 8) {
        float xv[8];
#pragma unroll
        for (int j = 0; j < 8; ++j) xv[j] = xrow[(size_t)(h + j) * 256 + w];
        a0 = fmaf(ms[h + 0], xv[0], a0);
        a1 = fmaf(ms[h + 1], xv[1], a1);
        a2 = fmaf(ms[h + 2], xv[2], a2);
        a3 = fmaf(ms[h + 3], xv[3], a3);
        a0 = fmaf(ms[h + 4], xv[4], a0);
        a1 = fmaf(ms[h + 5], xv[5], a1);
        a2 = fmaf(ms[h + 6], xv[6], a2);
        a3 = fmaf(ms[h + 7], xv[7], a3);
    }
    float acc = (a0 + a1) + (a2 + a3);
    xw[((size_t)(b * LL) + w) * DM + d] = acc * (1.0f / 256.0f);
}

// ---------------- phase E: swizzled ----------------
__global__ __launch_bounds__(256) void k_final(const float* __restrict__ mw,
                                               const float* __restrict__ x0,
                                               float* __restrict__ out) {
    __shared__ float ms[LL];
    int b, d; unswz(blockIdx.x, b, d);
    int bd = (b << 8) | d;
    int tid = threadIdx.x;
    ms[tid] = mw[((size_t)(b * LL) + tid) * DM + d];
    __syncthreads();

    int w4 = tid & 63;
    int hq = tid >> 6;
    float4 mv = *(const float4*)(ms + (w4 << 2));
    const float4* xin = (const float4*)(x0 + (size_t)bd * 65536);
    float4* oout = (float4*)(out + (size_t)bd * 65536);
#pragma unroll 4
    for (int hi = 0; hi < 64; ++hi) {
        int h = hi * 4 + hq;
        size_t idx = (size_t)h * 64 + w4;
        float4 xv = xin[idx];
        float4 o;
        o.x = mv.x * xv.x;
        o.y = mv.y * xv.y;
        o.z = mv.z * xv.z;
        o.w = mv.w * xv.w;
        oout[idx] = o;
    }
}

extern "C" void kernel_launch(void* const* d_in, const int* in_sizes, int n_in,
                              void* d_out, int out_size, void* d_ws, size_t ws_size,
                              hipStream_t stream) {
    const float* x0      = (const float*)d_in[0];
    const float* in_w    = (const float*)d_in[1];
    const float* conv_w  = (const float*)d_in[2];
    const float* conv_b  = (const float*)d_in[3];
    const float* xproj_w = (const float*)d_in[4];
    const float* dt_w    = (const float*)d_in[5];
    const float* dt_b    = (const float*)d_in[6];
    const float* A_log   = (const float*)d_in[7];
    const float* Dp      = (const float*)d_in[8];
    const float* out_w   = (const float*)d_in[9];
    float* out = (float*)d_out;

    float* S0   = (float*)d_ws;
    float* Sout = S0 + 262144;
    float* Wf   = Sout + 262144;
    float* xz   = Wf + 524288;
    float* xx   = xz + 1048576;
    float* xdbl = xx + 524288;
    float* ygT  = xdbl + 49152;

    const float* out_w1 = out_w + 131072;

    auto run_model = [&](const float* inb, float* outb) {
        k_gemm_nt64<<<256, 256, 0, stream>>>(inb, in_w, xz);
        k_mid<<<256, 256, 0, stream>>>(xz, conv_w, conv_b, xproj_w, xx, xdbl);
        k_scan<<<512, 256, 0, stream>>>(xx, xdbl, xz, A_log, Dp, dt_w, dt_b, ygT);
        k_gemm_tn64<<<256, 256, 0, stream>>>(ygT, Wf, xz);
        k_mid<<<256, 256, 0, stream>>>(xz, conv_w + 2048, conv_b + 512,
                                       xproj_w + 24576, xx, xdbl);
        k_scan<<<512, 256, 0, stream>>>(xx, xdbl, xz, A_log + 8192, Dp + 512,
                                        dt_w + 8192, dt_b + 512, ygT);
        k_gemm_tn32<<<256, 256, 0, stream>>>(ygT, out_w1, outb);
    };

    k_meanw_prep<<<1536, 256, 0, stream>>>(x0, in_w + 262144, out_w, S0, Wf);
    run_model(S0, Sout);
    k_fuse_mean_h<<<NBL, 256, 0, stream>>>(Sout, x0, S0);
    run_model(S0, Sout);
    k_final<<<NBL, 256, 0, stream>>>(Sout, x0, out);
}

// Round 13
// 472.713 us; speedup vs baseline: 3.9431x; 1.0133x over previous
//
#include <hip/hip_runtime.h>
#include <math.h>

#define BSZ 4
#define DM 256
#define LL 256
#define DI 512
#define NBL (BSZ * LL)  // 1024

__device__ __forceinline__ float fast_rcp(float x) { return __builtin_amdgcn_rcpf(x); }
__device__ __forceinline__ float fast_sig(float x) { return fast_rcp(1.0f + __expf(-x)); }

// XCD batch-locality swizzle: launch index j -> (batch b, intra-batch i)
__device__ __forceinline__ void unswz(int j, int& b, int& i) {
    b = (j & 7) >> 1;
    i = ((j >> 3) << 1) | (j & 1);
}

// ---------------- dispatch 1: mean over W (blocks 0..1023, swizzled) + Wf prep ----------------
__global__ __launch_bounds__(256) void k_meanw_prep(const float* __restrict__ x0,
                                                    const float* __restrict__ in_w1,
                                                    const float* __restrict__ out_w0,
                                                    float* __restrict__ S0,
                                                    float* __restrict__ Wf) {
    __shared__ float smem[1664];
    int bl = blockIdx.x;
    int tid = threadIdx.x;
    if (bl < 1024) {
        int b, i; unswz(bl, b, i);
        int rowblk = (b << 8) | i;
        int wv = tid >> 6, lane = tid & 63;
        const float4* x4 = (const float4*)x0;
        int rbase = rowblk * 256 + wv * 64;
        for (int i0 = 0; i0 < 64; i0 += 8) {
            float s[8];
#pragma unroll
            for (int j = 0; j < 8; ++j) {
                float4 v = x4[(size_t)(rbase + i0 + j) * 64 + lane];
                s[j] = (v.x + v.y) + (v.z + v.w);
            }
#pragma unroll
            for (int j = 0; j < 8; ++j) {
#pragma unroll
                for (int m = 32; m >= 1; m >>= 1) s[j] += __shfl_xor(s[j], m);
            }
            if (lane == 0) {
#pragma unroll
                for (int j = 0; j < 8; ++j) {
                    int rr = rbase + i0 + j;
                    int bb = rr >> 16, d = (rr >> 8) & 255, h = rr & 255;
                    S0[((size_t)(bb * LL) + h) * DM + d] = s[j] * (1.0f / 256.0f);
                }
            }
        }
    } else {
        float* As = smem;
        float* Bs = smem + 576;
        int t = bl - 1024;
        int e0 = (t >> 4) * 32, k0c = (t & 15) * 32;
        int tx = tid & 15, ty = tid >> 4;
        float acc00 = 0.f, acc01 = 0.f, acc10 = 0.f, acc11 = 0.f;
        for (int dm0 = 0; dm0 < 256; dm0 += 16) {
            float4 v;
            if (tid < 128) {
                int r = tid >> 2, q = tid & 3;
                v = *(const float4*)(in_w1 + (size_t)(e0 + r) * 256 + dm0 + 4 * q);
            } else {
                int idx = tid - 128;
                int r = idx >> 3, q = idx & 7;
                v = *(const float4*)(out_w0 + (size_t)(dm0 + r) * 512 + k0c + 4 * q);
            }
            __syncthreads();
            if (tid < 128) {
                int r = tid >> 2, q = tid & 3;
                As[(4 * q + 0) * 36 + r] = v.x;
                As[(4 * q + 1) * 36 + r] = v.y;
                As[(4 * q + 2) * 36 + r] = v.z;
                As[(4 * q + 3) * 36 + r] = v.w;
            } else {
                int idx = tid - 128;
                int r = idx >> 3, q = idx & 7;
                Bs[r * 36 + 4 * q + 0] = v.x;
                Bs[r * 36 + 4 * q + 1] = v.y;
                Bs[r * 36 + 4 * q + 2] = v.z;
                Bs[r * 36 + 4 * q + 3] = v.w;
            }
            __syncthreads();
#pragma unroll
            for (int kk = 0; kk < 16; ++kk) {
                float2 a = *(const float2*)(As + kk * 36 + 2 * ty);
                float2 b2 = *(const float2*)(Bs + kk * 36 + 2 * tx);
                acc00 = fmaf(a.x, b2.x, acc00);
                acc01 = fmaf(a.x, b2.y, acc01);
                acc10 = fmaf(a.y, b2.x, acc10);
                acc11 = fmaf(a.y, b2.y, acc11);
            }
        }
        float* c0 = Wf + (size_t)(e0 + 2 * ty) * 512 + k0c + 2 * tx;
        c0[0] = acc00; c0[1] = acc01;
        c0[512] = acc10; c0[513] = acc11;
    }
}

// ---------------- in-proj GEMM: 64x64 tile, 4x4 micro, K=256, grid 256 ----------------
__global__ __launch_bounds__(256) void k_gemm_nt64(const float* __restrict__ A,
                                                   const float* __restrict__ Bw,
                                                   float* __restrict__ C) {
    __shared__ float As[16][68];
    __shared__ float Bs[16][68];
    int tid = threadIdx.x;
    int b, i; unswz(blockIdx.x, b, i);
    int m0 = b * 256 + (i >> 4) * 64;
    int n0 = (i & 15) * 64;
    int tx = tid & 15, ty = tid >> 4;
    int r = tid >> 2, kq = (tid & 3) * 4;

    const float* pa = A + (size_t)(m0 + r) * 256 + kq;
    const float* pb = Bw + (size_t)(n0 + r) * 256 + kq;
    float4 ra = *(const float4*)pa;
    float4 rb = *(const float4*)pb;

    float acc[4][4];
#pragma unroll
    for (int ii = 0; ii < 4; ++ii)
#pragma unroll
        for (int jj = 0; jj < 4; ++jj) acc[ii][jj] = 0.0f;

    for (int k0 = 0; k0 < 256; k0 += 16) {
        __syncthreads();
        As[kq + 0][r] = ra.x; As[kq + 1][r] = ra.y; As[kq + 2][r] = ra.z; As[kq + 3][r] = ra.w;
        Bs[kq + 0][r] = rb.x; Bs[kq + 1][r] = rb.y; Bs[kq + 2][r] = rb.z; Bs[kq + 3][r] = rb.w;
        __syncthreads();
        if (k0 + 16 < 256) {
            ra = *(const float4*)(pa + k0 + 16);
            rb = *(const float4*)(pb + k0 + 16);
        }
#pragma unroll
        for (int kk = 0; kk < 16; ++kk) {
            float4 a4 = *(const float4*)(&As[kk][ty * 4]);
            float4 b4 = *(const float4*)(&Bs[kk][tx * 4]);
            float aa[4] = {a4.x, a4.y, a4.z, a4.w};
            float bb[4] = {b4.x, b4.y, b4.z, b4.w};
#pragma unroll
            for (int ii = 0; ii < 4; ++ii)
#pragma unroll
                for (int jj = 0; jj < 4; ++jj)
                    acc[ii][jj] = fmaf(aa[ii], bb[jj], acc[ii][jj]);
        }
    }
#pragma unroll
    for (int ii = 0; ii < 4; ++ii) {
        float4 o;
        o.x = acc[ii][0]; o.y = acc[ii][1]; o.z = acc[ii][2]; o.w = acc[ii][3];
        *(float4*)(C + (size_t)(m0 + ty * 4 + ii) * 1024 + n0 + tx * 4) = o;
    }
}

// ---------------- transition GEMM: 64x64 tile, 4x4 micro, K=512, grid 256 ----------------
__global__ __launch_bounds__(256) void k_gemm_tn64(const float* __restrict__ At,
                                                   const float* __restrict__ Bw,
                                                   float* __restrict__ C) {
    __shared__ float As[16][68];
    __shared__ float Bs[16][68];
    int tid = threadIdx.x;
    int b, i; unswz(blockIdx.x, b, i);
    int l0 = (i >> 4) * 64;
    int n0 = (i & 15) * 64;
    int m0 = b * 256 + l0;
    int tx = tid & 15, ty = tid >> 4;
    int rkk = tid >> 4, mq = (tid & 15) * 4;
    int rn = tid >> 2, dq = (tid & 3) * 4;

    const float* pa = At + ((size_t)(b * 512) + rkk) * 256 + l0 + mq;
    const float* pb = Bw + (size_t)(n0 + rn) * 512 + dq;
    float4 ra = *(const float4*)pa;
    float4 rb = *(const float4*)pb;

    float acc[4][4];
#pragma unroll
    for (int ii = 0; ii < 4; ++ii)
#pragma unroll
        for (int jj = 0; jj < 4; ++jj) acc[ii][jj] = 0.0f;

    for (int d0 = 0; d0 < 512; d0 += 16) {
        __syncthreads();
        *(float4*)(&As[rkk][mq]) = ra;
        Bs[dq + 0][rn] = rb.x; Bs[dq + 1][rn] = rb.y; Bs[dq + 2][rn] = rb.z; Bs[dq + 3][rn] = rb.w;
        __syncthreads();
        if (d0 + 16 < 512) {
            ra = *(const float4*)(pa + (size_t)(d0 + 16) * 256);
            rb = *(const float4*)(pb + d0 + 16);
        }
#pragma unroll
        for (int kk = 0; kk < 16; ++kk) {
            float4 a4 = *(const float4*)(&As[kk][ty * 4]);
            float4 b4 = *(const float4*)(&Bs[kk][tx * 4]);
            float aa[4] = {a4.x, a4.y, a4.z, a4.w};
            float bb[4] = {b4.x, b4.y, b4.z, b4.w};
#pragma unroll
            for (int ii = 0; ii < 4; ++ii)
#pragma unroll
                for (int jj = 0; jj < 4; ++jj)
                    acc[ii][jj] = fmaf(aa[ii], bb[jj], acc[ii][jj]);
        }
    }
#pragma unroll
    for (int ii = 0; ii < 4; ++ii) {
        float4 o;
        o.x = acc[ii][0]; o.y = acc[ii][1]; o.z = acc[ii][2]; o.w = acc[ii][3];
        *(float4*)(C + (size_t)(m0 + ty * 4 + ii) * 1024 + n0 + tx * 4) = o;
    }
}

// ---------------- fused conv+silu+xproj: 256 blocks x 4 (b,l) each ----------------
__global__ __launch_bounds__(256) void k_mid(const float* __restrict__ xz,
                                             const float* __restrict__ cw,
                                             const float* __restrict__ cb,
                                             const float* __restrict__ xpw,
                                             float* __restrict__ xx,
                                             float* __restrict__ xdbl) {
    __shared__ float xs[DI];
    __shared__ float pr[256];
    int tid = threadIdx.x;
    int b = (blockIdx.x & 7) >> 1;
    int ib = ((blockIdx.x >> 3) << 1) | (blockIdx.x & 1);   // 0..63

    for (int k = 0; k < 4; ++k) {
        int l = ib + 64 * k;
        int bl = (b << 8) | l;
        __syncthreads();
#pragma unroll
        for (int c = 0; c < 2; ++c) {
            int d = tid + 256 * c;
            float4 w4 = *(const float4*)(cw + d * 4);
            float acc = cb[d];
#pragma unroll
            for (int kk = 0; kk < 4; ++kk) {
                int ls = l + kk - 3;
                float v = (ls >= 0) ? xz[((size_t)(b * LL + ls)) * 1024 + d] : 0.0f;
                acc = fmaf(((const float*)&w4)[kk], v, acc);
            }
            float v = acc * fast_sig(acc);
            xs[d] = v;
            xx[(size_t)bl * DI + d] = v;
        }
        __syncthreads();

        int e = tid >> 2, c2 = tid & 3;
        float a = 0.0f;
        if (e < 48) {
            const float4* xv4 = (const float4*)(xs + c2 * 128);
            const float4* wv4 = (const float4*)(xpw + (size_t)e * DI + c2 * 128);
#pragma unroll 8
            for (int q = 0; q < 32; ++q) {
                float4 x4 = xv4[q], p4 = wv4[q];
                a = fmaf(x4.x, p4.x, a);
                a = fmaf(x4.y, p4.y, a);
                a = fmaf(x4.z, p4.z, a);
                a = fmaf(x4.w, p4.w, a);
            }
        }
        pr[tid] = a;
        __syncthreads();
        if (tid < 48)
            xdbl[(size_t)bl * 48 + tid] = pr[4 * tid] + pr[4 * tid + 1] + pr[4 * tid + 2] + pr[4 * tid + 3];
    }
}

// ---------------- selective scan: 512 blocks x 4 sequences each ----------------
__global__ __launch_bounds__(256) void k_scan(const float* __restrict__ xx,
                                              const float* __restrict__ xdbl,
                                              const float* __restrict__ xz,
                                              const float* __restrict__ Alog,
                                              const float* __restrict__ Dp,
                                              const float* __restrict__ dtw,
                                              const float* __restrict__ dtb,
                                              float* __restrict__ ygT) {
    __shared__ float yred[4][LL];
    __shared__ float us[LL];
    int tid = threadIdx.x;
    int lane = tid & 63, w = tid >> 6;
    int b = (blockIdx.x & 7) >> 1;
    int ib = ((blockIdx.x >> 3) << 1) | (blockIdx.x & 1);   // 0..127
    int l0 = lane * 4;

    for (int kq = 0; kq < 4; ++kq) {
        int d = ib + 128 * kq;
        int seq = b * DI + d;
        __syncthreads();

        const float* xd0 = xdbl + ((size_t)(b * LL) + l0) * 48;
        const float* wr = dtw + d * 16;
        float4 w0 = *(const float4*)(wr + 0);
        float4 w1 = *(const float4*)(wr + 4);
        float4 w2 = *(const float4*)(wr + 8);
        float4 w3 = *(const float4*)(wr + 12);
        float bias = dtb[d];

        float dt[4], u[4], dtu[4], P[4];
#pragma unroll
        for (int i = 0; i < 4; ++i) {
            const float* xr = xd0 + i * 48;
            float4 a0 = *(const float4*)(xr + 0);
            float4 a1 = *(const float4*)(xr + 4);
            float4 a2 = *(const float4*)(xr + 8);
            float4 a3 = *(const float4*)(xr + 12);
            float acc = bias;
            acc = fmaf(a0.x, w0.x, acc); acc = fmaf(a0.y, w0.y, acc);
            acc = fmaf(a0.z, w0.z, acc); acc = fmaf(a0.w, w0.w, acc);
            acc = fmaf(a1.x, w1.x, acc); acc = fmaf(a1.y, w1.y, acc);
            acc = fmaf(a1.z, w1.z, acc); acc = fmaf(a1.w, w1.w, acc);
            acc = fmaf(a2.x, w2.x, acc); acc = fmaf(a2.y, w2.y, acc);
            acc = fmaf(a2.z, w2.z, acc); acc = fmaf(a2.w, w2.w, acc);
            acc = fmaf(a3.x, w3.x, acc); acc = fmaf(a3.y, w3.y, acc);
            acc = fmaf(a3.z, w3.z, acc); acc = fmaf(a3.w, w3.w, acc);
            dt[i] = (acc > 20.0f) ? acc : __logf(1.0f + __expf(acc));
            u[i] = xx[((size_t)(b * LL) + l0 + i) * DI + d];
            dtu[i] = dt[i] * u[i];
        }

        P[0] = dt[0]; P[1] = P[0] + dt[1]; P[2] = P[1] + dt[2]; P[3] = P[2] + dt[3];
        float s = P[3];
#pragma unroll
        for (int off = 1; off < 64; off <<= 1) {
            float t = __shfl_up(s, off);
            if (lane >= off) s += t;
        }
        float base = s - P[3];
        float dt_end = __shfl(s, 63);
        float Dtc[4];
#pragma unroll
        for (int i = 0; i < 4; ++i) Dtc[i] = P[i] + base;

        if (w == 0) {
#pragma unroll
            for (int i = 0; i < 4; ++i) us[l0 + i] = u[i];
        }

        float4 Al = *(const float4*)(Alog + d * 16 + 4 * w);
        float A[4] = {-__expf(Al.x), -__expf(Al.y), -__expf(Al.z), -__expf(Al.w)};
        float Bv[4][4], Cv[4][4];
#pragma unroll
        for (int i = 0; i < 4; ++i) {
            float4 bq = *(const float4*)(xd0 + i * 48 + 16 + 4 * w);
            float4 cq = *(const float4*)(xd0 + i * 48 + 32 + 4 * w);
            Bv[i][0] = bq.x; Bv[i][1] = bq.y; Bv[i][2] = bq.z; Bv[i][3] = bq.w;
            Cv[i][0] = cq.x; Cv[i][1] = cq.y; Cv[i][2] = cq.z; Cv[i][3] = cq.w;
        }

        float y[4] = {0.f, 0.f, 0.f, 0.f};
#pragma unroll
        for (int c = 0; c < 4; ++c) {
            float Ac = A[c];
            float dAc[4], t[4];
#pragma unroll
            for (int i = 0; i < 4; ++i) {
                dAc[i] = __expf(Ac * (dt_end - Dtc[i]));
                t[i] = dtu[i] * Bv[i][c] * dAc[i];
            }
            float p0 = t[0], p1 = p0 + t[1], p2 = p1 + t[2], p3 = p2 + t[3];
            float ss = p3;
#pragma unroll
            for (int off = 1; off < 64; off <<= 1) {
                float tt = __shfl_up(ss, off);
                if (lane >= off) ss += tt;
            }
            float baseT = ss - p3;
            y[0] = fmaf((p0 + baseT) * fast_rcp(dAc[0] + 1e-12f), Cv[0][c], y[0]);
            y[1] = fmaf((p1 + baseT) * fast_rcp(dAc[1] + 1e-12f), Cv[1][c], y[1]);
            y[2] = fmaf((p2 + baseT) * fast_rcp(dAc[2] + 1e-12f), Cv[2][c], y[2]);
            y[3] = fmaf((p3 + baseT) * fast_rcp(dAc[3] + 1e-12f), Cv[3][c], y[3]);
        }
#pragma unroll
        for (int i = 0; i < 4; ++i) yred[w][l0 + i] = y[i];
        __syncthreads();

        int l = tid;
        float ysum = yred[0][l] + yred[1][l] + yred[2][l] + yred[3][l];
        float yv = fmaf(us[l], Dp[d], ysum);
        float res = xz[((size_t)(b * LL) + l) * 1024 + DI + d];
        ygT[(size_t)seq * LL + l] = yv * res * fast_sig(res);
    }
}

// ---------------- out-proj matvec (one Sout column) into LDS ----------------
__device__ __forceinline__ void outproj_col(const float* __restrict__ ygT,
                                            const float* __restrict__ w1row,
                                            int b, int tid,
                                            float* ws, float* ms) {
    ws[tid] = w1row[tid];
    ws[tid + 256] = w1row[tid + 256];
    __syncthreads();
    const float* yb = ygT + (size_t)(b * 512) * 256 + tid;   // + dd*256
    float a0 = 0.f, a1 = 0.f, a2 = 0.f, a3 = 0.f;
#pragma unroll 2
    for (int dd = 0; dd < 512; dd += 8) {
        float v0 = yb[(dd + 0) * 256], v1 = yb[(dd + 1) * 256];
        float v2 = yb[(dd + 2) * 256], v3 = yb[(dd + 3) * 256];
        float v4 = yb[(dd + 4) * 256], v5 = yb[(dd + 5) * 256];
        float v6 = yb[(dd + 6) * 256], v7 = yb[(dd + 7) * 256];
        a0 = fmaf(v0, ws[dd + 0], a0);
        a1 = fmaf(v1, ws[dd + 1], a1);
        a2 = fmaf(v2, ws[dd + 2], a2);
        a3 = fmaf(v3, ws[dd + 3], a3);
        a0 = fmaf(v4, ws[dd + 4], a0);
        a1 = fmaf(v5, ws[dd + 5], a1);
        a2 = fmaf(v6, ws[dd + 6], a2);
        a3 = fmaf(v7, ws[dd + 7], a3);
    }
    ms[tid] = (a0 + a1) + (a2 + a3);
    __syncthreads();
}

// ---------------- phase C fused with out-proj: block (b,d_model) ----------------
__global__ __launch_bounds__(256) void k_outproj_fuse_mean_h(const float* __restrict__ ygT,
                                                             const float* __restrict__ w1,
                                                             const float* __restrict__ x0,
                                                             float* __restrict__ xw) {
    __shared__ float ws[512];
    __shared__ float ms[LL];
    int b, d; unswz(blockIdx.x, b, d);
    int bd = (b << 8) | d;
    int tid = threadIdx.x;
    outproj_col(ygT, w1 + (size_t)d * 512, b, tid, ws, ms);

    int w = tid;
    const float* xrow = x0 + (size_t)bd * 65536;
    float a0 = 0.0f, a1 = 0.0f, a2 = 0.0f, a3 = 0.0f;
    for (int h = 0; h < 256; h += 8) {
        float xv[8];
#pragma unroll
        for (int j = 0; j < 8; ++j) xv[j] = xrow[(size_t)(h + j) * 256 + w];
        a0 = fmaf(ms[h + 0], xv[0], a0);
        a1 = fmaf(ms[h + 1], xv[1], a1);
        a2 = fmaf(ms[h + 2], xv[2], a2);
        a3 = fmaf(ms[h + 3], xv[3], a3);
        a0 = fmaf(ms[h + 4], xv[4], a0);
        a1 = fmaf(ms[h + 5], xv[5], a1);
        a2 = fmaf(ms[h + 6], xv[6], a2);
        a3 = fmaf(ms[h + 7], xv[7], a3);
    }
    float acc = (a0 + a1) + (a2 + a3);
    xw[((size_t)(b * LL) + w) * DM + d] = acc * (1.0f / 256.0f);
}

// ---------------- phase E fused with out-proj: block (b,d_model) ----------------
__global__ __launch_bounds__(256) void k_outproj_final(const float* __restrict__ ygT,
                                                       const float* __restrict__ w1,
                                                       const float* __restrict__ x0,
                                                       float* __restrict__ out) {
    __shared__ float ws[512];
    __shared__ float ms[LL];
    int b, d; unswz(blockIdx.x, b, d);
    int bd = (b << 8) | d;
    int tid = threadIdx.x;
    outproj_col(ygT, w1 + (size_t)d * 512, b, tid, ws, ms);

    int w4 = tid & 63;
    int hq = tid >> 6;
    float4 mv = *(const float4*)(ms + (w4 << 2));
    const float4* xin = (const float4*)(x0 + (size_t)bd * 65536);
    float4* oout = (float4*)(out + (size_t)bd * 65536);
#pragma unroll 4
    for (int hi = 0; hi < 64; ++hi) {
        int h = hi * 4 + hq;
        size_t idx = (size_t)h * 64 + w4;
        float4 xv = xin[idx];
        float4 o;
        o.x = mv.x * xv.x;
        o.y = mv.y * xv.y;
        o.z = mv.z * xv.z;
        o.w = mv.w * xv.w;
        oout[idx] = o;
    }
}

extern "C" void kernel_launch(void* const* d_in, const int* in_sizes, int n_in,
                              void* d_out, int out_size, void* d_ws, size_t ws_size,
                              hipStream_t stream) {
    const float* x0      = (const float*)d_in[0];
    const float* in_w    = (const float*)d_in[1];
    const float* conv_w  = (const float*)d_in[2];
    const float* conv_b  = (const float*)d_in[3];
    const float* xproj_w = (const float*)d_in[4];
    const float* dt_w    = (const float*)d_in[5];
    const float* dt_b    = (const float*)d_in[6];
    const float* A_log   = (const float*)d_in[7];
    const float* Dp      = (const float*)d_in[8];
    const float* out_w   = (const float*)d_in[9];
    float* out = (float*)d_out;

    float* S0   = (float*)d_ws;
    float* Wf   = S0 + 262144;
    float* xz   = Wf + 524288;
    float* xx   = xz + 1048576;
    float* xdbl = xx + 524288;
    float* ygT  = xdbl + 49152;

    const float* out_w1 = out_w + 131072;

    auto run_model_core = [&](const float* inb) {
        k_gemm_nt64<<<256, 256, 0, stream>>>(inb, in_w, xz);
        k_mid<<<256, 256, 0, stream>>>(xz, conv_w, conv_b, xproj_w, xx, xdbl);
        k_scan<<<512, 256, 0, stream>>>(xx, xdbl, xz, A_log, Dp, dt_w, dt_b, ygT);
        k_gemm_tn64<<<256, 256, 0, stream>>>(ygT, Wf, xz);
        k_mid<<<256, 256, 0, stream>>>(xz, conv_w + 2048, conv_b + 512,
                                       xproj_w + 24576, xx, xdbl);
        k_scan<<<512, 256, 0, stream>>>(xx, xdbl, xz, A_log + 8192, Dp + 512,
                                        dt_w + 8192, dt_b + 512, ygT);
    };

    k_meanw_prep<<<1536, 256, 0, stream>>>(x0, in_w + 262144, out_w, S0, Wf);
    run_model_core(S0);
    k_outproj_fuse_mean_h<<<NBL, 256, 0, stream>>>(ygT, out_w1, x0, S0);
    run_model_core(S0);
    k_outproj_final<<<NBL, 256, 0, stream>>>(ygT, out_w1, x0, out);
}